// Round 5
// baseline (3222.321 us; speedup 1.0000x reference)
//
#include <hip/hip_runtime.h>

typedef unsigned short u16;
typedef short short8 __attribute__((ext_vector_type(8)));
typedef float f32x4 __attribute__((ext_vector_type(4)));
typedef unsigned short u16x4 __attribute__((ext_vector_type(4)));

#define B_  256
#define T_  600
#define TC_ 75    // time chunk (8 chunks)
#define HID 200
#define G4  800
#define HSTR 232  // hbuf row stride (u16): 464B -> 2-way bank aliasing only (free)
#define WCOLS 224 // padded whh row length (u16)

__device__ __forceinline__ float bf2f(u16 u) {
  union { unsigned int i; float f; } v; v.i = ((unsigned int)u) << 16; return v.f;
}
__device__ __forceinline__ u16 f2bf(float f) {
  union { float f; unsigned int i; } v; v.f = f;
  unsigned int r = v.i + 0x7FFFu + ((v.i >> 16) & 1u);
  return (u16)(r >> 16);
}
__device__ __forceinline__ float sigm(float x) {
  float e = __expf(-x);
  return __builtin_amdgcn_rcpf(1.f + e);
}

// single per-step barrier: LDS writes must be visible; global ops stay in flight
#define BARRIER_LGKM() asm volatile("s_waitcnt lgkmcnt(0)\n\ts_barrier" ::: "memory")

// ---------------------------------------------------------------------------
// Pad / permute / downcast f32 weights into aligned bf16 scratch.
// ---------------------------------------------------------------------------
__global__ __launch_bounds__(256) void padperm_k(const float* __restrict__ src,
                                                 u16* __restrict__ dst,
                                                 int rows, int srows, int scols,
                                                 int dcols, int perm) {
  int idx = blockIdx.x * 256 + threadIdx.x;
  if (idx >= rows * dcols) return;
  int r = idx / dcols, c = idx - r * dcols;
  int sr = perm ? ((r & 3) * 200 + (r >> 2)) : r;
  dst[idx] = (r < srows && c < scols) ? f2bf(src[(size_t)sr * scols + c]) : (u16)0;
}

// ---------------------------------------------------------------------------
// Transpose chunk: x [B][129][600] f32 -> xTq [B][TC_][160] bf16, window t0.
// ---------------------------------------------------------------------------
__global__ __launch_bounds__(256) void transpose_k(const float* __restrict__ x,
                                                   u16* __restrict__ xTq, int t0) {
  __shared__ u16 tile[129 * 65];
  const int b = blockIdx.y;
  const int tt0 = blockIdx.x * 64;
  const int tid = threadIdx.x;
  for (int idx = tid; idx < 129 * 64; idx += 256) {
    int i = idx >> 6, tt = idx & 63;
    int t = t0 + tt0 + tt;
    tile[i * 65 + tt] = (tt0 + tt < TC_ && t < T_)
        ? f2bf(x[((size_t)b * 129 + i) * T_ + t]) : (u16)0;
  }
  __syncthreads();
  for (int idx = tid; idx < 64 * 160; idx += 256) {
    int tt = idx / 160, i = idx - tt * 160;
    if (tt0 + tt < TC_)
      xTq[((size_t)b * TC_ + tt0 + tt) * 160 + i] = (i < 129) ? tile[i * 65 + tt] : (u16)0;
  }
}

// ---------------------------------------------------------------------------
// 256-thread GEMM: out = ACT(A @ W^T + bias). Used for gemm2 / fc1 / fc2.
// ---------------------------------------------------------------------------
template<int ASRC, int LDK, int NSRC, int NSTORE, int BPERM, int ACT, int OUTM, int CHUNK>
__global__ __launch_bounds__(256, 2) void gemm_k(
    const u16* __restrict__ A, const u16* __restrict__ W,
    const float* __restrict__ B1, const float* __restrict__ B2,
    void* __restrict__ outv, int ldout, int t0) {
  constexpr int NCH = LDK / 8;
  constexpr int KT = LDK / 32;
  __shared__ u16 la[128 * LDK];
  __shared__ float lbias[128];
  const int tid = threadIdx.x;
  const int mb = blockIdx.x, nb = blockIdx.y;

  for (int idx = tid; idx < 128 * NCH; idx += 256) {
    int row = idx / NCH, c = idx - row * NCH;
    int m = mb * 128 + row;
    size_t arow;
    if (CHUNK) {
      int b = m / TC_;
      int tt = m - b * TC_;
      arow = (size_t)b * T_ + t0 + tt;
    } else {
      arow = (size_t)m;
    }
    short8 v = (short8)0;
    if (8 * c + 8 <= ASRC)
      v = *(const short8*)(A + arow * ASRC + 8 * c);
    *(short8*)(la + row * LDK + 8 * c) = v;
  }
  if (tid < 128) {
    int p = nb * 128 + tid;
    float bv = 0.f;
    if (p < NSRC) {
      int orig = BPERM ? ((p & 3) * 200 + (p >> 2)) : p;
      bv = B1[orig];
      if (BPERM) bv += B2[orig];
    }
    lbias[tid] = bv;
  }
  __syncthreads();

  const int w = tid >> 6, l = tid & 63;
  const int quad = l >> 4, l15 = l & 15;
  const int mq = (w >> 1) * 64, nq = (w & 1) * 64;

  const u16* wrow[4];
#pragma unroll
  for (int nt = 0; nt < 4; ++nt) {
    int p = nb * 128 + nq + nt * 16 + l15;
    wrow[nt] = W + (size_t)((p < NSRC) ? p : 0) * LDK;
  }

  f32x4 acc[4][4];
#pragma unroll
  for (int i = 0; i < 4; ++i)
#pragma unroll
    for (int j = 0; j < 4; ++j) acc[i][j] = (f32x4)0.f;

#pragma unroll
  for (int kt = 0; kt < KT; ++kt) {
    const int k0 = kt * 32 + quad * 8;
    short8 bf[4];
#pragma unroll
    for (int nt = 0; nt < 4; ++nt) bf[nt] = *(const short8*)(wrow[nt] + k0);
    short8 af[4];
#pragma unroll
    for (int mt = 0; mt < 4; ++mt)
      af[mt] = *(const short8*)(la + (mq + mt * 16 + l15) * LDK + k0);
#pragma unroll
    for (int mt = 0; mt < 4; ++mt)
#pragma unroll
      for (int nt = 0; nt < 4; ++nt)
        acc[mt][nt] = __builtin_amdgcn_mfma_f32_16x16x32_bf16(af[mt], bf[nt],
                                                              acc[mt][nt], 0, 0, 0);
  }

#pragma unroll
  for (int mt = 0; mt < 4; ++mt) {
#pragma unroll
    for (int nt = 0; nt < 4; ++nt) {
#pragma unroll
      for (int r = 0; r < 4; ++r) {
        int rowl = mq + mt * 16 + quad * 4 + r;
        int coln = nq + nt * 16 + l15;
        int pg = nb * 128 + coln;
        if (pg < NSTORE) {
          float v = (pg < NSRC) ? (acc[mt][nt][r] + lbias[coln]) : 0.f;
          if (ACT == 1) v = fmaxf(v, 0.f);
          if (ACT == 2) v = sigm(v);
          size_t m = (size_t)mb * 128 + rowl;
          if (OUTM == 0) {
            ((u16*)outv)[m * (size_t)ldout + pg] = f2bf(v);
          } else {
            int b = (int)(m / T_);
            int t = (int)(m - (size_t)b * T_);
            ((float*)outv)[((size_t)b * 129 + pg) * T_ + t] = v;
          }
        }
      }
    }
  }
}

// ---------------------------------------------------------------------------
// Persistent LSTM recurrence body. 8 waves (512 thr) pinned at 2 waves/EU ->
// 256-VGPR budget. R0-verified partition: waves 0,1 own 7 N-tiles, waves 2..7
// own 6; k-tiles 0..5 register-resident (wreg[7][6] = 168 VGPR); k-tile 6
// (cols 192..199) as compact LDS table read by quad0 lanes. hbuf double-
// buffered: ONE lgkm barrier per step.
// ---------------------------------------------------------------------------
__device__ __forceinline__ void rec_body(const u16* __restrict__ xg,
                                         const u16* __restrict__ whh,
                                         u16* __restrict__ houtb, int hb_stride,
                                         const u16* __restrict__ hprevb, int hp_bstride,
                                         float* __restrict__ cst, int has_prev,
                                         int blk, char* smem) {
  u16* hb = (u16*)smem;                  // [2][16*HSTR] = 14848 B
  u16* w6 = (u16*)(smem + 14848);        // [50][128]    = 12800 B

  const int tid = threadIdx.x;
  const int w = tid >> 6, l = tid & 63;
  const int quad = l >> 4, l15 = l & 15;
  const int b0 = blk * 16;
  const int nslots = (w < 2) ? 7 : 6;    // 50 N-tiles over 8 waves

  // ---- prologue: weight caches ----
  short8 wreg[7][6];
#pragma unroll
  for (int s = 0; s < 7; ++s) {
    int tile = w + 8 * s;
    int p = tile * 16 + l15;
    int orig = (p & 3) * 200 + (p >> 2);
    const u16* wb = whh + (size_t)orig * WCOLS;
#pragma unroll
    for (int kk = 0; kk < 6; ++kk) {
      short8 v = (short8)0;
      if (s < nslots) v = *(const short8*)(wb + kk * 32 + quad * 8);
      wreg[s][kk] = v;
    }
    if (s < nslots && quad == 0)   // kt6 compact: cols 192..199
      *(short8*)(w6 + tile * 128 + l15 * 8) = *(const short8*)(wb + 192);
  }
  // zero pad cols 200..231 of both h buffers
  for (int i = tid; i < 1024; i += 512) {
    int bsel = i >> 9, r = (i >> 5) & 15, cc = i & 31;
    hb[bsel * (16 * HSTR) + r * HSTR + 200 + cc] = 0;
  }

  // ---- state: slot s -> (batch l15, unit (w+8s)*4+quad) ----
  float c[7]; u16 hreg[7];
#pragma unroll
  for (int s = 0; s < 7; ++s) { c[s] = 0.f; hreg[s] = 0; }
  float* cstp = cst + (size_t)(b0 + l15) * HID;
  if (has_prev) {
#pragma unroll
    for (int s = 0; s < 7; ++s)
      if (s < nslots) {
        int unit = (w + 8 * s) * 4 + quad;
        hreg[s] = hprevb[(size_t)(b0 + l15) * hp_bstride + unit];
        c[s] = cstp[unit];
      }
  }

  // xg gather base + first prefetch
  const u16* xptr = xg + (size_t)(b0 + l15) * TC_ * G4 + w * 16 + quad * 4;
  u16x4 xv[7];
#pragma unroll
  for (int s = 0; s < 7; ++s)
    xv[s] = (s < nslots) ? *(const u16x4*)(xptr + s * 128) : (u16x4)0;

  u16* hout = houtb + (size_t)(b0 + l15) * hb_stride;

  // publish h(-1) into buffer 0
#pragma unroll
  for (int s = 0; s < 7; ++s)
    if (s < nslots)
      hb[l15 * HSTR + (w + 8 * s) * 4 + quad] = hreg[s];

  __syncthreads();  // prologue fence (weights, pad zeros, h(-1) visible)

  for (int t = 0; t < TC_; ++t) {
    const u16* hr = hb + (t & 1) * (16 * HSTR);
    u16* hw = hb + ((t + 1) & 1) * (16 * HSTR);

    f32x4 acc[7];
#pragma unroll
    for (int s = 0; s < 7; ++s) acc[s] = (f32x4)0.f;

#pragma unroll
    for (int kk = 0; kk < 6; ++kk) {
      short8 hf = *(const short8*)(hr + l15 * HSTR + kk * 32 + quad * 8);
#pragma unroll
      for (int s = 0; s < 7; ++s)
        if (s < nslots)
          acc[s] = __builtin_amdgcn_mfma_f32_16x16x32_bf16(wreg[s][kk], hf, acc[s], 0, 0, 0);
    }
    {  // tail k-tile 6: h cols 192..199 real, 200..223 zero-padded
      short8 hf = *(const short8*)(hr + l15 * HSTR + 192 + quad * 8);
#pragma unroll
      for (int s = 0; s < 7; ++s)
        if (s < nslots) {
          short8 wz = (short8)0;
          if (quad == 0)
            wz = *(const short8*)(w6 + (w + 8 * s) * 128 + l15 * 8);
          acc[s] = __builtin_amdgcn_mfma_f32_16x16x32_bf16(wz, hf, acc[s], 0, 0, 0);
        }
    }

    // ---- lane-local cell update: acc[s][0..3] = i,f,g,o pre-acts ----
#pragma unroll
    for (int s = 0; s < 7; ++s) {
      if (s < nslots) {
        float vi = acc[s][0] + bf2f(xv[s][0]);
        float vf = acc[s][1] + bf2f(xv[s][1]);
        float vg = acc[s][2] + bf2f(xv[s][2]);
        float vo = acc[s][3] + bf2f(xv[s][3]);
        float iv = sigm(vi);
        float fv = sigm(vf);
        float gv = 2.f * sigm(2.f * vg) - 1.f;  // tanh
        float ov = sigm(vo);
        float cn = fv * c[s] + iv * gv;
        c[s] = cn;
        float th = 2.f * sigm(2.f * cn) - 1.f;
        hreg[s] = f2bf(ov * th);
      }
    }

    // publish h(t) into the other buffer
#pragma unroll
    for (int s = 0; s < 7; ++s)
      if (s < nslots)
        hw[l15 * HSTR + (w + 8 * s) * 4 + quad] = hreg[s];

    // global h(t) store (stays in flight across the barrier)
#pragma unroll
    for (int s = 0; s < 7; ++s)
      if (s < nslots)
        hout[(size_t)t * HID + (w + 8 * s) * 4 + quad] = hreg[s];

    // prefetch xg(t+1)
    if (t + 1 < TC_) {
      const u16* xp = xptr + (size_t)(t + 1) * G4;
#pragma unroll
      for (int s = 0; s < 7; ++s)
        if (s < nslots) xv[s] = *(const u16x4*)(xp + s * 128);
    }
    BARRIER_LGKM();  // single per-step barrier
  }

  // carry state
#pragma unroll
  for (int s = 0; s < 7; ++s)
    if (s < nslots) cstp[(w + 8 * s) * 4 + quad] = c[s];
}

// ---------------------------------------------------------------------------
// 512-thread GEMM body for layer-1 input GEMM (xTq @ wp1^T + bias -> xg).
// Block = 128 rows x 256 cols (8 waves = 2m x 4n of 64x64), 3 M-passes.
// Grid 200 = 50 m-triples x 4 n-blocks; fused grid stays <= 256.
// ---------------------------------------------------------------------------
__device__ __forceinline__ void gemm1_body(const u16* __restrict__ A,
                                           const u16* __restrict__ W,
                                           const float* __restrict__ B1,
                                           const float* __restrict__ B2,
                                           u16* __restrict__ out, int bb,
                                           char* smem) {
  u16* la = (u16*)smem;                    // [128][160] = 40960 B
  float* lbias = (float*)(smem + 40960);   // [256]      =  1024 B
  const int tid = threadIdx.x;
  const int mt3 = bb >> 2, nb = bb & 3;

  if (tid < 256) {
    int p = nb * 256 + tid;
    float bv = 0.f;
    if (p < 800) { int orig = (p & 3) * 200 + (p >> 2); bv = B1[orig] + B2[orig]; }
    lbias[tid] = bv;
  }

  const int w = tid >> 6, l = tid & 63;
  const int quad = l >> 4, l15 = l & 15;
  const int mq = (w >> 2) * 64, nq = (w & 3) * 64;

  const u16* wrow[4];
#pragma unroll
  for (int nt = 0; nt < 4; ++nt) {
    int p = nb * 256 + nq + nt * 16 + l15;
    wrow[nt] = W + (size_t)((p < 800) ? p : 0) * 160;
  }

  for (int mi = 0; mi < 3; ++mi) {
    const int mb = mt3 * 3 + mi;
    if (mi) __syncthreads();  // drain previous pass's la reads
    for (int idx = tid; idx < 128 * 20; idx += 512) {
      int row = idx / 20, cc = idx - row * 20;
      *(short8*)(la + row * 160 + 8 * cc) =
          *(const short8*)(A + (size_t)(mb * 128 + row) * 160 + 8 * cc);
    }
    __syncthreads();

    f32x4 acc[4][4];
#pragma unroll
    for (int i = 0; i < 4; ++i)
#pragma unroll
      for (int j = 0; j < 4; ++j) acc[i][j] = (f32x4)0.f;

#pragma unroll
    for (int kt = 0; kt < 5; ++kt) {
      const int k0 = kt * 32 + quad * 8;
      short8 bf[4];
#pragma unroll
      for (int nt = 0; nt < 4; ++nt) bf[nt] = *(const short8*)(wrow[nt] + k0);
      short8 af[4];
#pragma unroll
      for (int mt = 0; mt < 4; ++mt)
        af[mt] = *(const short8*)(la + (mq + mt * 16 + l15) * 160 + k0);
#pragma unroll
      for (int mt = 0; mt < 4; ++mt)
#pragma unroll
        for (int nt = 0; nt < 4; ++nt)
          acc[mt][nt] = __builtin_amdgcn_mfma_f32_16x16x32_bf16(af[mt], bf[nt],
                                                                acc[mt][nt], 0, 0, 0);
    }

#pragma unroll
    for (int mt = 0; mt < 4; ++mt) {
#pragma unroll
      for (int nt = 0; nt < 4; ++nt) {
#pragma unroll
        for (int r = 0; r < 4; ++r) {
          int rowl = mq + mt * 16 + quad * 4 + r;
          int coln = nq + nt * 16 + l15;
          int pg = nb * 256 + coln;
          if (pg < 800) {
            float v = acc[mt][nt][r] + lbias[coln];
            out[(size_t)(mb * 128 + rowl) * 800 + pg] = f2bf(v);
          }
        }
      }
    }
  }
}

// ---------------------------------------------------------------------------
// Fused launch: blocks [0,nA) rec layer-1 chunk, [nA,nA+nB) rec layer-2
// chunk, rest run the (independent) layer-1 input GEMM for the next chunk.
// waves_per_eu(2,2) PINS occupancy at 2 waves/SIMD -> 256-VGPR budget; the
// single-arg launch_bounds hint was ignored by the allocator (R2/R3: VGPR=64
// with spills). This is the fix for the spilled weight cache.
// ---------------------------------------------------------------------------
__global__ __attribute__((amdgpu_flat_work_group_size(512, 512),
                          amdgpu_waves_per_eu(2, 2)))
void fused_k(
    const u16* __restrict__ xgA, const u16* __restrict__ whhA,
    u16* __restrict__ hA, int hsA, const u16* __restrict__ hpA, int hpsA,
    float* __restrict__ cstA, int prevA,
    const u16* __restrict__ xgB, const u16* __restrict__ whhB,
    u16* __restrict__ hB, int hsB, const u16* __restrict__ hpB, int hpsB,
    float* __restrict__ cstB, int prevB,
    const u16* __restrict__ gA, const u16* __restrict__ gW,
    const float* __restrict__ gB1, const float* __restrict__ gB2,
    u16* __restrict__ gOut,
    int nA, int nB, int nG) {
  __shared__ __align__(16) char smem[43008];
  int bb = blockIdx.x;
  if (bb < nA) { rec_body(xgA, whhA, hA, hsA, hpA, hpsA, cstA, prevA, bb, smem); return; }
  bb -= nA;
  if (bb < nB) { rec_body(xgB, whhB, hB, hsB, hpB, hpsB, cstB, prevB, bb, smem); return; }
  bb -= nB;
  if (bb < nG) gemm1_body(gA, gW, gB1, gB2, gOut, bb, smem);
}

// ---------------------------------------------------------------------------
extern "C" void kernel_launch(void* const* d_in, const int* in_sizes, int n_in,
                              void* d_out, int out_size, void* d_ws, size_t ws_size,
                              hipStream_t stream) {
  (void)in_sizes; (void)n_in; (void)out_size; (void)ws_size;
  const float* x     = (const float*)d_in[0];
  const float* w_ih1 = (const float*)d_in[1];
  const float* w_hh1 = (const float*)d_in[2];
  const float* b_ih1 = (const float*)d_in[3];
  const float* b_hh1 = (const float*)d_in[4];
  const float* w_ih2 = (const float*)d_in[5];
  const float* w_hh2 = (const float*)d_in[6];
  const float* b_ih2 = (const float*)d_in[7];
  const float* b_hh2 = (const float*)d_in[8];
  const float* fc1_w = (const float*)d_in[9];
  const float* fc1_b = (const float*)d_in[10];
  const float* fc2_w = (const float*)d_in[11];
  const float* fc2_b = (const float*)d_in[12];
  float* out = (float*)d_out;

  // workspace layout (bytes, 16-aligned); total ~176.9 MB
  char* ws = (char*)d_ws;
  u16*   xg0   = (u16*)(ws);                     //  30,720,000  [256][75][800]
  u16*   xg1   = (u16*)(ws + 30720000LL);        //  30,720,000
  u16*   xgB   = (u16*)(ws + 61440000LL);        //  30,720,000
  u16*   h2    = (u16*)(ws + 92160000LL);        //  61,440,000  [256][600][200]
  u16*   h1c0  = (u16*)(ws + 153600000LL);       //   7,680,000  [256][75][200]
  u16*   h1c1  = (u16*)(ws + 161280000LL);       //   7,680,000
  u16*   xTq   = (u16*)(ws + 168960000LL);       //   6,144,000  [256][75][160]
  float* cst1  = (float*)(ws + 175104000LL);     //     204,800  [256][200] f32
  float* cst2  = (float*)(ws + 175308800LL);     //     204,800
  u16*   wp1   = (u16*)(ws + 175513600LL);       //     256,000  [800][160]
  u16*   wp2   = (u16*)(ws + 175769600LL);       //     358,400  [800][224]
  u16*   fc1p  = (u16*)(ws + 176128000LL);       //      57,792  [129][224]
  u16*   fc2p  = (u16*)(ws + 176185792LL);       //      41,280  [129][160]
  u16*   whh1c = (u16*)(ws + 176227072LL);       //     358,400  [800][224]
  u16*   whh2c = (u16*)(ws + 176585472LL);       //     358,400
  u16*   y1    = (u16*)(ws);                     // reuse xg0/xg1 after pipeline

  u16* xgp[2] = {xg0, xg1};
  u16* h1c[2] = {h1c0, h1c1};

  padperm_k<<<(800 * 160 + 255) / 256, 256, 0, stream>>>(w_ih1, wp1, 800, 800, 129, 160, 1);
  padperm_k<<<(800 * 224 + 255) / 256, 256, 0, stream>>>(w_ih2, wp2, 800, 800, 200, 224, 1);
  padperm_k<<<(129 * 224 + 255) / 256, 256, 0, stream>>>(fc1_w, fc1p, 129, 129, 200, 224, 0);
  padperm_k<<<(129 * 160 + 255) / 256, 256, 0, stream>>>(fc2_w, fc2p, 129, 129, 129, 160, 0);
  padperm_k<<<(800 * 224 + 255) / 256, 256, 0, stream>>>(w_hh1, whh1c, 800, 800, 200, 224, 0);
  padperm_k<<<(800 * 224 + 255) / 256, 256, 0, stream>>>(w_hh2, whh2c, 800, 800, 200, 224, 0);

  // chunk 0 input GEMM (gemm-only fused launch)
  transpose_k<<<dim3(2, 256), 256, 0, stream>>>(x, xTq, 0);
  fused_k<<<dim3(200), 512, 0, stream>>>(
      xg0, whh1c, h1c0, 15000, h1c0, 15000, cst1, 0,
      xgB, whh2c, h2, 120000, h2, 120000, cst2, 0,
      xTq, wp1, b_ih1, b_hh1, xg0,
      0, 0, 200);

  // software pipeline: stage i runs rec1(chunk i) || rec2(chunk i-1) || gemm1(chunk i+1)
  for (int i = 0; i <= 8; ++i) {
    if (i < 7)
      transpose_k<<<dim3(2, 256), 256, 0, stream>>>(x, xTq, (i + 1) * TC_);
    const int nA = (i < 8) ? 16 : 0;
    const int nB = (i >= 1) ? 16 : 0;
    const int nG = (i < 7) ? 200 : 0;
    const int ib = (i >= 1) ? (i - 1) : 0;  // layer-2 chunk index
    fused_k<<<dim3(nA + nB + nG), 512, 0, stream>>>(
        /*A: layer-1 chunk i*/
        xgp[i & 1], whh1c, h1c[i & 1], 15000,
        (i >= 1) ? (h1c[(i - 1) & 1] + 74 * HID) : h1c[0], 15000, cst1, (i >= 1) ? 1 : 0,
        /*B: layer-2 chunk i-1*/
        xgB, whh2c, h2 + (size_t)ib * 75 * HID, 120000,
        (ib >= 1) ? (h2 + ((size_t)ib * 75 - 1) * HID) : h2, 120000, cst2, (ib >= 1) ? 1 : 0,
        /*G: layer-1 input GEMM chunk i+1*/
        xTq, wp1, b_ih1, b_hh1, xgp[(i + 1) & 1],
        nA, nB, nG);
    if (i < 8)  // layer-2 input GEMM for chunk i (consumed by next fused launch)
      gemm_k<200, 224, 800, 800, 1, 0, 0, 0>
          <<<dim3(150, 7), 256, 0, stream>>>(h1c[i & 1], wp2, b_ih2, b_hh2, xgB, 800, 0);
  }

  // y1 = relu(h2 @ fc1^T + b)
  gemm_k<200, 224, 129, 144, 0, 1, 0, 0>
      <<<dim3(1200, 2), 256, 0, stream>>>(h2, fc1p, fc1_b, fc1_b, y1, 144, 0);
  // out = sigmoid(y1 @ fc2^T + b), f32 scatter to [B][129][T]
  gemm_k<144, 160, 129, 129, 0, 2, 1, 0>
      <<<dim3(1200, 2), 256, 0, stream>>>(y1, fc2p, fc2_b, fc2_b, out, 0, 0);
}

// Round 7
// 3194.864 us; speedup vs baseline: 1.0086x; 1.0086x over previous
//
#include <hip/hip_runtime.h>

typedef unsigned short u16;
typedef short short8 __attribute__((ext_vector_type(8)));
typedef float f32x4 __attribute__((ext_vector_type(4)));
typedef unsigned short u16x4 __attribute__((ext_vector_type(4)));

#define B_  256
#define T_  600
#define TC_ 75    // time chunk (8 chunks)
#define HID 200
#define G4  800
#define HSTR 232  // hbuf row stride (u16): 464B -> 2-way bank aliasing only (free)

__device__ __forceinline__ float bf2f(u16 u) {
  union { unsigned int i; float f; } v; v.i = ((unsigned int)u) << 16; return v.f;
}
__device__ __forceinline__ u16 f2bf(float f) {
  union { float f; unsigned int i; } v; v.f = f;
  unsigned int r = v.i + 0x7FFFu + ((v.i >> 16) & 1u);
  return (u16)(r >> 16);
}
__device__ __forceinline__ float sigm(float x) {
  float e = __expf(-x);
  return __builtin_amdgcn_rcpf(1.f + e);
}

// single per-step barrier: LDS writes must be visible; global ops stay in flight
#define BARRIER_LGKM() asm volatile("s_waitcnt lgkmcnt(0)\n\ts_barrier" ::: "memory")

// ---------------------------------------------------------------------------
// Pad / permute / downcast f32 weights into aligned bf16 scratch.
// ---------------------------------------------------------------------------
__global__ __launch_bounds__(256) void padperm_k(const float* __restrict__ src,
                                                 u16* __restrict__ dst,
                                                 int rows, int srows, int scols,
                                                 int dcols, int perm) {
  int idx = blockIdx.x * 256 + threadIdx.x;
  if (idx >= rows * dcols) return;
  int r = idx / dcols, c = idx - r * dcols;
  int sr = perm ? ((r & 3) * 200 + (r >> 2)) : r;
  dst[idx] = (r < srows && c < scols) ? f2bf(src[(size_t)sr * scols + c]) : (u16)0;
}

// ---------------------------------------------------------------------------
// Transpose chunk: x [B][129][600] f32 -> xTq [B][TC_][160] bf16, window t0.
// ---------------------------------------------------------------------------
__global__ __launch_bounds__(256) void transpose_k(const float* __restrict__ x,
                                                   u16* __restrict__ xTq, int t0) {
  __shared__ u16 tile[129 * 65];
  const int b = blockIdx.y;
  const int tt0 = blockIdx.x * 64;
  const int tid = threadIdx.x;
  for (int idx = tid; idx < 129 * 64; idx += 256) {
    int i = idx >> 6, tt = idx & 63;
    int t = t0 + tt0 + tt;
    tile[i * 65 + tt] = (tt0 + tt < TC_ && t < T_)
        ? f2bf(x[((size_t)b * 129 + i) * T_ + t]) : (u16)0;
  }
  __syncthreads();
  for (int idx = tid; idx < 64 * 160; idx += 256) {
    int tt = idx / 160, i = idx - tt * 160;
    if (tt0 + tt < TC_)
      xTq[((size_t)b * TC_ + tt0 + tt) * 160 + i] = (i < 129) ? tile[i * 65 + tt] : (u16)0;
  }
}

// ---------------------------------------------------------------------------
// GEMM: out = ACT(A @ W^T + bias).
// ---------------------------------------------------------------------------
template<int ASRC, int LDK, int NSRC, int NSTORE, int BPERM, int ACT, int OUTM, int CHUNK>
__global__ __launch_bounds__(256, 2) void gemm_k(
    const u16* __restrict__ A, const u16* __restrict__ W,
    const float* __restrict__ B1, const float* __restrict__ B2,
    void* __restrict__ outv, int ldout, int t0) {
  constexpr int NCH = LDK / 8;
  constexpr int KT = LDK / 32;
  __shared__ u16 la[128 * LDK];
  __shared__ float lbias[128];
  const int tid = threadIdx.x;
  const int mb = blockIdx.x, nb = blockIdx.y;

  for (int idx = tid; idx < 128 * NCH; idx += 256) {
    int row = idx / NCH, c = idx - row * NCH;
    int m = mb * 128 + row;
    size_t arow;
    if (CHUNK) {
      int b = m / TC_;
      int tt = m - b * TC_;
      arow = (size_t)b * T_ + t0 + tt;
    } else {
      arow = (size_t)m;
    }
    short8 v = (short8)0;
    if (8 * c + 8 <= ASRC)
      v = *(const short8*)(A + arow * ASRC + 8 * c);
    *(short8*)(la + row * LDK + 8 * c) = v;
  }
  if (tid < 128) {
    int p = nb * 128 + tid;
    float bv = 0.f;
    if (p < NSRC) {
      int orig = BPERM ? ((p & 3) * 200 + (p >> 2)) : p;
      bv = B1[orig];
      if (BPERM) bv += B2[orig];
    }
    lbias[tid] = bv;
  }
  __syncthreads();

  const int w = tid >> 6, l = tid & 63;
  const int quad = l >> 4, l15 = l & 15;
  const int mq = (w >> 1) * 64, nq = (w & 1) * 64;

  const u16* wrow[4];
#pragma unroll
  for (int nt = 0; nt < 4; ++nt) {
    int p = nb * 128 + nq + nt * 16 + l15;
    wrow[nt] = W + (size_t)((p < NSRC) ? p : 0) * LDK;
  }

  f32x4 acc[4][4];
#pragma unroll
  for (int i = 0; i < 4; ++i)
#pragma unroll
    for (int j = 0; j < 4; ++j) acc[i][j] = (f32x4)0.f;

#pragma unroll
  for (int kt = 0; kt < KT; ++kt) {
    const int k0 = kt * 32 + quad * 8;
    short8 bf[4];
#pragma unroll
    for (int nt = 0; nt < 4; ++nt) bf[nt] = *(const short8*)(wrow[nt] + k0);
    short8 af[4];
#pragma unroll
    for (int mt = 0; mt < 4; ++mt)
      af[mt] = *(const short8*)(la + (mq + mt * 16 + l15) * LDK + k0);
#pragma unroll
    for (int mt = 0; mt < 4; ++mt)
#pragma unroll
      for (int nt = 0; nt < 4; ++nt)
        acc[mt][nt] = __builtin_amdgcn_mfma_f32_16x16x32_bf16(af[mt], bf[nt],
                                                              acc[mt][nt], 0, 0, 0);
  }

#pragma unroll
  for (int mt = 0; mt < 4; ++mt) {
#pragma unroll
    for (int nt = 0; nt < 4; ++nt) {
#pragma unroll
      for (int r = 0; r < 4; ++r) {
        int rowl = mq + mt * 16 + quad * 4 + r;
        int coln = nq + nt * 16 + l15;
        int pg = nb * 128 + coln;
        if (pg < NSTORE) {
          float v = (pg < NSRC) ? (acc[mt][nt][r] + lbias[coln]) : 0.f;
          if (ACT == 1) v = fmaxf(v, 0.f);
          if (ACT == 2) v = sigm(v);
          size_t m = (size_t)mb * 128 + rowl;
          if (OUTM == 0) {
            ((u16*)outv)[m * (size_t)ldout + pg] = f2bf(v);
          } else {
            int b = (int)(m / T_);
            int t = (int)(m - (size_t)b * T_);
            ((float*)outv)[((size_t)b * 129 + pg) * T_ + t] = v;
          }
        }
      }
    }
  }
}

// ---------------------------------------------------------------------------
// Persistent LSTM recurrence, 16 waves (1024 thr), pinned 4 waves/EU ->
// 128-VGPR budget. 50 N-tiles over 16 waves: waves 0,1 own 4 slots (tiles
// w, w+16, w+32, w+48), waves 2..15 own 3. k-tiles 0..3 register-resident
// (wreg[4][4] = 64 VGPR); k-tiles 4,5 in LDS with PER-LANE-CONTIGUOUS
// layout (lane*16B -> conflict-free, unlike R2's 8-way layout); k-tile 6
// compact quad0 table (2-way, free). hbuf double-buffered, ONE lgkm
// barrier per step (R2-verified sync structure).
// ---------------------------------------------------------------------------
__device__ __forceinline__ void rec_body(const u16* __restrict__ xgq,
                                         const u16* __restrict__ whh,
                                         u16* __restrict__ hout,
                                         float* __restrict__ cst,
                                         int t0, int blk, char* smem) {
  u16* hb  = (u16*)smem;                    // [2][16*HSTR]   = 14,848 B
  u16* w45 = (u16*)(smem + 14848);          // [50][2][512]u16 = 102,400 B
  u16* w6  = (u16*)(smem + 117248);         // [50][128]u16    = 12,800 B

  const int tid = threadIdx.x;
  const int w = tid >> 6, l = tid & 63;
  const int quad = l >> 4, l15 = l & 15;
  const int b0 = blk * 16;
  const bool four = (w < 2);                // waves 0,1 own tile 48/49 as slot 3

  // ---- prologue: weight caches ----
  short8 wreg[4][4];                        // k-tiles 0..3
#pragma unroll
  for (int s = 0; s < 4; ++s) {
    const bool act = (s < 3) || four;
    int tile = w + 16 * s;
    int p = tile * 16 + l15;
    int orig = (p & 3) * 200 + (p >> 2);
    const u16* wb = whh + (size_t)orig * HID;
#pragma unroll
    for (int kk = 0; kk < 4; ++kk)
      wreg[s][kk] = act ? *(const short8*)(wb + kk * 32 + quad * 8) : (short8)0;
    if (act) {
#pragma unroll
      for (int j = 0; j < 2; ++j)           // kt4,5 -> per-lane-contiguous LDS
        *(short8*)(w45 + (tile * 2 + j) * 512 + l * 8) =
            *(const short8*)(wb + (4 + j) * 32 + quad * 8);
      if (quad == 0)                        // kt6 compact: cols 192..199
        *(short8*)(w6 + tile * 128 + l15 * 8) = *(const short8*)(wb + 192);
    }
  }
  // zero pad cols 200..231 of both h buffers (1024 entries, one per thread)
  { int bsel = tid >> 9, r = (tid >> 5) & 15, cc = tid & 31;
    hb[bsel * (16 * HSTR) + r * HSTR + 200 + cc] = 0; }

  // ---- state: slot s -> (batch l15, unit (w+16s)*4+quad) ----
  float c[4]; u16 hreg[4];
#pragma unroll
  for (int s = 0; s < 4; ++s) { c[s] = 0.f; hreg[s] = 0; }
  float* cstp = cst + (size_t)(b0 + l15) * HID;
  if (t0 != 0) {
#pragma unroll
    for (int s = 0; s < 3; ++s) {
      int unit = (w + 16 * s) * 4 + quad;
      hreg[s] = hout[((size_t)(b0 + l15) * T_ + (t0 - 1)) * HID + unit];
      c[s] = cstp[unit];
    }
    if (four) {
      int unit = (w + 48) * 4 + quad;
      hreg[3] = hout[((size_t)(b0 + l15) * T_ + (t0 - 1)) * HID + unit];
      c[3] = cstp[unit];
    }
  }

  // xg gather base + first prefetch (slot stride = 16 tiles = 256 u16)
  const u16* xptr = xgq + (size_t)(b0 + l15) * TC_ * G4 + w * 16 + quad * 4;
  u16x4 xv[4];
#pragma unroll
  for (int s = 0; s < 3; ++s) xv[s] = *(const u16x4*)(xptr + s * 256);
  xv[3] = four ? *(const u16x4*)(xptr + 768) : (u16x4)0;

  u16* hptr = hout + ((size_t)(b0 + l15) * T_ + t0) * HID;

  // publish h(-1) into buffer 0
#pragma unroll
  for (int s = 0; s < 3; ++s)
    hb[l15 * HSTR + (w + 16 * s) * 4 + quad] = hreg[s];
  if (four)
    hb[l15 * HSTR + (w + 48) * 4 + quad] = hreg[3];

  __syncthreads();  // prologue fence (weights, pad zeros, h(-1) visible)

  for (int t = 0; t < TC_; ++t) {
    const u16* hr = hb + (t & 1) * (16 * HSTR);
    u16* hw = hb + ((t + 1) & 1) * (16 * HSTR);

    f32x4 acc[4];
#pragma unroll
    for (int s = 0; s < 4; ++s) acc[s] = (f32x4)0.f;

#pragma unroll
    for (int kk = 0; kk < 4; ++kk) {        // k-tiles 0..3 from registers
      short8 hf = *(const short8*)(hr + l15 * HSTR + kk * 32 + quad * 8);
      acc[0] = __builtin_amdgcn_mfma_f32_16x16x32_bf16(wreg[0][kk], hf, acc[0], 0, 0, 0);
      acc[1] = __builtin_amdgcn_mfma_f32_16x16x32_bf16(wreg[1][kk], hf, acc[1], 0, 0, 0);
      acc[2] = __builtin_amdgcn_mfma_f32_16x16x32_bf16(wreg[2][kk], hf, acc[2], 0, 0, 0);
      if (four)
        acc[3] = __builtin_amdgcn_mfma_f32_16x16x32_bf16(wreg[3][kk], hf, acc[3], 0, 0, 0);
    }
#pragma unroll
    for (int j = 0; j < 2; ++j) {           // k-tiles 4,5 from LDS (conflict-free)
      short8 hf = *(const short8*)(hr + l15 * HSTR + (4 + j) * 32 + quad * 8);
#pragma unroll
      for (int s = 0; s < 3; ++s) {
        short8 wz = *(const short8*)(w45 + ((w + 16 * s) * 2 + j) * 512 + l * 8);
        acc[s] = __builtin_amdgcn_mfma_f32_16x16x32_bf16(wz, hf, acc[s], 0, 0, 0);
      }
      if (four) {
        short8 wz = *(const short8*)(w45 + ((w + 48) * 2 + j) * 512 + l * 8);
        acc[3] = __builtin_amdgcn_mfma_f32_16x16x32_bf16(wz, hf, acc[3], 0, 0, 0);
      }
    }
    {  // tail k-tile 6: h cols 192..199 real, 200..223 zero-padded
      short8 hf = *(const short8*)(hr + l15 * HSTR + 192 + quad * 8);
#pragma unroll
      for (int s = 0; s < 3; ++s) {
        short8 wz = (short8)0;
        if (quad == 0)
          wz = *(const short8*)(w6 + (w + 16 * s) * 128 + l15 * 8);
        acc[s] = __builtin_amdgcn_mfma_f32_16x16x32_bf16(wz, hf, acc[s], 0, 0, 0);
      }
      if (four) {
        short8 wz = (short8)0;
        if (quad == 0)
          wz = *(const short8*)(w6 + (w + 48) * 128 + l15 * 8);
        acc[3] = __builtin_amdgcn_mfma_f32_16x16x32_bf16(wz, hf, acc[3], 0, 0, 0);
      }
    }

    // ---- lane-local cell update: acc[s][0..3] = i,f,g,o pre-acts ----
#pragma unroll
    for (int s = 0; s < 4; ++s) {
      if (s == 3 && !four) break;
      float vi = acc[s][0] + bf2f(xv[s][0]);
      float vf = acc[s][1] + bf2f(xv[s][1]);
      float vg = acc[s][2] + bf2f(xv[s][2]);
      float vo = acc[s][3] + bf2f(xv[s][3]);
      float iv = sigm(vi);
      float fv = sigm(vf);
      float gv = 2.f * sigm(2.f * vg) - 1.f;  // tanh
      float ov = sigm(vo);
      float cn = fv * c[s] + iv * gv;
      c[s] = cn;
      float th = 2.f * sigm(2.f * cn) - 1.f;
      hreg[s] = f2bf(ov * th);
    }

    // publish h(t) into the other buffer
#pragma unroll
    for (int s = 0; s < 3; ++s)
      hw[l15 * HSTR + (w + 16 * s) * 4 + quad] = hreg[s];
    if (four)
      hw[l15 * HSTR + (w + 48) * 4 + quad] = hreg[3];

    // global h(t) store (stays in flight; vmcnt never drained in-loop)
#pragma unroll
    for (int s = 0; s < 3; ++s)
      hptr[(size_t)t * HID + (w + 16 * s) * 4 + quad] = hreg[s];
    if (four)
      hptr[(size_t)t * HID + (w + 48) * 4 + quad] = hreg[3];

    // prefetch xg(t+1)
    if (t + 1 < TC_) {
      const u16* xp = xptr + (size_t)(t + 1) * G4;
#pragma unroll
      for (int s = 0; s < 3; ++s) xv[s] = *(const u16x4*)(xp + s * 256);
      if (four) xv[3] = *(const u16x4*)(xp + 768);
    }
    BARRIER_LGKM();  // single per-step barrier
  }

  // carry state
#pragma unroll
  for (int s = 0; s < 3; ++s) cstp[(w + 16 * s) * 4 + quad] = c[s];
  if (four) cstp[(w + 48) * 4 + quad] = c[3];
}

// Dual-role recurrence: blocks [0,nA) run param set A (layer-1 chunk),
// blocks [nA,grid) run set B (layer-2 chunk), on disjoint CUs.
__global__ __attribute__((amdgpu_flat_work_group_size(1024, 1024),
                          amdgpu_waves_per_eu(4, 4)))
void recp_k(const u16* __restrict__ xgA, const u16* __restrict__ whhA,
            u16* __restrict__ hA, float* __restrict__ cstA, int t0A,
            const u16* __restrict__ xgB, const u16* __restrict__ whhB,
            u16* __restrict__ hB, float* __restrict__ cstB, int t0B, int nA) {
  __shared__ __align__(16) char smem[130048];
  const int bb = blockIdx.x;
  if (bb < nA) rec_body(xgA, whhA, hA, cstA, t0A, bb, smem);
  else         rec_body(xgB, whhB, hB, cstB, t0B, bb - nA, smem);
}

// ---------------------------------------------------------------------------
extern "C" void kernel_launch(void* const* d_in, const int* in_sizes, int n_in,
                              void* d_out, int out_size, void* d_ws, size_t ws_size,
                              hipStream_t stream) {
  (void)in_sizes; (void)n_in; (void)out_size; (void)ws_size;
  const float* x     = (const float*)d_in[0];
  const float* w_ih1 = (const float*)d_in[1];
  const float* w_hh1 = (const float*)d_in[2];
  const float* b_ih1 = (const float*)d_in[3];
  const float* b_hh1 = (const float*)d_in[4];
  const float* w_ih2 = (const float*)d_in[5];
  const float* w_hh2 = (const float*)d_in[6];
  const float* b_ih2 = (const float*)d_in[7];
  const float* b_hh2 = (const float*)d_in[8];
  const float* fc1_w = (const float*)d_in[9];
  const float* fc1_b = (const float*)d_in[10];
  const float* fc2_w = (const float*)d_in[11];
  const float* fc2_b = (const float*)d_in[12];
  float* out = (float*)d_out;

  // workspace layout (bytes, 16-aligned); total ~192.2 MB
  char* ws = (char*)d_ws;
  u16*   xgA   = (u16*)(ws);                     //  30,720,000  [256][75][800]
  u16*   xgB   = (u16*)(ws + 30720000LL);        //  30,720,000
  u16*   h1    = (u16*)(ws + 61440000LL);        //  61,440,000  [256][600][200]
  u16*   h2    = (u16*)(ws + 122880000LL);       //  61,440,000
  u16*   xTq   = (u16*)(ws + 184320000LL);       //   6,144,000  [256][75][160]
  float* cst1  = (float*)(ws + 190464000LL);     //     204,800  [256][200] f32
  float* cst2  = (float*)(ws + 190668800LL);     //     204,800
  u16*   wp1   = (u16*)(ws + 190873600LL);       //     256,000  [800][160]
  u16*   wp2   = (u16*)(ws + 191129600LL);       //     358,400  [800][224]
  u16*   fc1p  = (u16*)(ws + 191488000LL);       //      57,792  [129][224]
  u16*   fc2p  = (u16*)(ws + 191545792LL);       //      41,280  [129][160]
  u16*   whh1c = (u16*)(ws + 191587072LL);       //     320,000  [800][200]
  u16*   whh2c = (u16*)(ws + 191907072LL);       //     320,000  [800][200]
  u16*   y1    = h1;                             // reuse after layer-2 GEMMs

  padperm_k<<<(800 * 160 + 255) / 256, 256, 0, stream>>>(w_ih1, wp1, 800, 800, 129, 160, 1);
  padperm_k<<<(800 * 224 + 255) / 256, 256, 0, stream>>>(w_ih2, wp2, 800, 800, 200, 224, 1);
  padperm_k<<<(129 * 224 + 255) / 256, 256, 0, stream>>>(fc1_w, fc1p, 129, 129, 200, 224, 0);
  padperm_k<<<(129 * 160 + 255) / 256, 256, 0, stream>>>(fc2_w, fc2p, 129, 129, 129, 160, 0);
  padperm_k<<<(800 * 200 + 255) / 256, 256, 0, stream>>>(w_hh1, whh1c, 800, 800, 200, 200, 0);
  padperm_k<<<(800 * 200 + 255) / 256, 256, 0, stream>>>(w_hh2, whh2c, 800, 800, 200, 200, 0);

  // ---- software pipeline: rec1(c_{i+1}) runs concurrently with rec2(c_i) ----
  // stage 0: layer-1 chunk 0 alone
  transpose_k<<<dim3(2, 256), 256, 0, stream>>>(x, xTq, 0);
  gemm_k<160, 160, 800, 800, 1, 0, 0, 0>
      <<<dim3(150, 7), 256, 0, stream>>>(xTq, wp1, b_ih1, b_hh1, xgA, 800, 0);
  recp_k<<<dim3(16), 1024, 0, stream>>>(xgA, whh1c, h1, cst1, 0,
                                        xgA, whh1c, h1, cst1, 0, 16);

  // stages 1..7: fused (layer-1 chunk i+1 || layer-2 chunk i)
  for (int i = 0; i < 7; ++i) {
    const int tA = (i + 1) * TC_;
    const int tB = i * TC_;
    transpose_k<<<dim3(2, 256), 256, 0, stream>>>(x, xTq, tA);
    gemm_k<160, 160, 800, 800, 1, 0, 0, 0>
        <<<dim3(150, 7), 256, 0, stream>>>(xTq, wp1, b_ih1, b_hh1, xgA, 800, 0);
    gemm_k<200, 224, 800, 800, 1, 0, 0, 1>
        <<<dim3(150, 7), 256, 0, stream>>>(h1, wp2, b_ih2, b_hh2, xgB, 800, tB);
    recp_k<<<dim3(32), 1024, 0, stream>>>(xgA, whh1c, h1, cst1, tA,
                                          xgB, whh2c, h2, cst2, tB, 16);
  }

  // stage 8: layer-2 chunk 7 alone
  gemm_k<200, 224, 800, 800, 1, 0, 0, 1>
      <<<dim3(150, 7), 256, 0, stream>>>(h1, wp2, b_ih2, b_hh2, xgB, 800, 7 * TC_);
  recp_k<<<dim3(16), 1024, 0, stream>>>(xgA, whh1c, h1, cst1, 0,
                                        xgB, whh2c, h2, cst2, 7 * TC_, 0);

  // y1 = relu(h2 @ fc1^T + b)
  gemm_k<200, 224, 129, 144, 0, 1, 0, 0>
      <<<dim3(1200, 2), 256, 0, stream>>>(h2, fc1p, fc1_b, fc1_b, y1, 144, 0);
  // out = sigmoid(y1 @ fc2^T + b), f32 scatter to [B][129][T]
  gemm_k<144, 160, 129, 129, 0, 2, 1, 0>
      <<<dim3(1200, 2), 256, 0, stream>>>(y1, fc2p, fc2_b, fc2_b, out, 0, 0);
}

// Round 8
// 2549.811 us; speedup vs baseline: 1.2637x; 1.2530x over previous
//
#include <hip/hip_runtime.h>

typedef unsigned short u16;
typedef short short8 __attribute__((ext_vector_type(8)));
typedef float f32x4 __attribute__((ext_vector_type(4)));
typedef unsigned short u16x4 __attribute__((ext_vector_type(4)));

#define B_  256
#define T_  600
#define TC_ 75    // time chunk (8 chunks)
#define HID 200
#define G4  800
#define HSTR 232  // hbuf row stride (u16): 464B -> 2-way bank aliasing only (free)
#define HROW (B_ * HID)  // 51200 u16 per time-row in [t][b][200] layout

__device__ __forceinline__ float bf2f(u16 u) {
  union { unsigned int i; float f; } v; v.i = ((unsigned int)u) << 16; return v.f;
}
__device__ __forceinline__ u16 f2bf(float f) {
  union { float f; unsigned int i; } v; v.f = f;
  unsigned int r = v.i + 0x7FFFu + ((v.i >> 16) & 1u);
  return (u16)(r >> 16);
}
__device__ __forceinline__ float sigm(float x) {
  float e = __expf(-x);
  return __builtin_amdgcn_rcpf(1.f + e);
}

// sync_a: LDS writes must be visible; global ops may remain in flight.
#define BARRIER_LGKM() asm volatile("s_waitcnt lgkmcnt(0)\n\ts_barrier" ::: "memory")
// sync_b: all LDS reads already register-consumed; just rendezvous.
#define BARRIER_ONLY() asm volatile("s_barrier" ::: "memory")

// ---------------------------------------------------------------------------
// Pad / permute / downcast f32 weights into aligned bf16 scratch.
// ---------------------------------------------------------------------------
__global__ __launch_bounds__(256) void padperm_k(const float* __restrict__ src,
                                                 u16* __restrict__ dst,
                                                 int rows, int srows, int scols,
                                                 int dcols, int perm) {
  int idx = blockIdx.x * 256 + threadIdx.x;
  if (idx >= rows * dcols) return;
  int r = idx / dcols, c = idx - r * dcols;
  int sr = perm ? ((r & 3) * 200 + (r >> 2)) : r;
  dst[idx] = (r < srows && c < scols) ? f2bf(src[(size_t)sr * scols + c]) : (u16)0;
}

// ---------------------------------------------------------------------------
// Transpose chunk: x [B][129][600] f32 -> xTq [B][TC_][160] bf16, window t0.
// ---------------------------------------------------------------------------
__global__ __launch_bounds__(256) void transpose_k(const float* __restrict__ x,
                                                   u16* __restrict__ xTq, int t0) {
  __shared__ u16 tile[129 * 65];
  const int b = blockIdx.y;
  const int tt0 = blockIdx.x * 64;
  const int tid = threadIdx.x;
  for (int idx = tid; idx < 129 * 64; idx += 256) {
    int i = idx >> 6, tt = idx & 63;
    int t = t0 + tt0 + tt;
    tile[i * 65 + tt] = (tt0 + tt < TC_ && t < T_)
        ? f2bf(x[((size_t)b * 129 + i) * T_ + t]) : (u16)0;
  }
  __syncthreads();
  for (int idx = tid; idx < 64 * 160; idx += 256) {
    int tt = idx / 160, i = idx - tt * 160;
    if (tt0 + tt < TC_)
      xTq[((size_t)b * TC_ + tt0 + tt) * 160 + i] = (i < 129) ? tile[i * 65 + tt] : (u16)0;
  }
}

// ---------------------------------------------------------------------------
// GEMM: out = ACT(A @ W^T + bias). AMAP selects the A-row mapping:
//   0: arow = m
//   1: m=(b,tt) in chunk -> arow = b*T_ + t0 + tt      (A = [b][600][*])
//   2: m=(b,tt) in chunk -> arow = tt*B_ + b           (A = chunk [tt][256][*])
//   3: m=(b,t)  full     -> arow = t*B_ + b            (A = [600][256][*])
// ---------------------------------------------------------------------------
template<int ASRC, int LDK, int NSRC, int NSTORE, int BPERM, int ACT, int OUTM, int AMAP>
__global__ __launch_bounds__(256, 2) void gemm_k(
    const u16* __restrict__ A, const u16* __restrict__ W,
    const float* __restrict__ B1, const float* __restrict__ B2,
    void* __restrict__ outv, int ldout, int t0) {
  constexpr int NCH = LDK / 8;
  constexpr int KT = LDK / 32;
  __shared__ u16 la[128 * LDK];
  __shared__ float lbias[128];
  const int tid = threadIdx.x;
  const int mb = blockIdx.x, nb = blockIdx.y;

  for (int idx = tid; idx < 128 * NCH; idx += 256) {
    int row = idx / NCH, c = idx - row * NCH;
    int m = mb * 128 + row;
    size_t arow;
    if (AMAP == 1) {
      int b = m / TC_; int tt = m - b * TC_;
      arow = (size_t)b * T_ + t0 + tt;
    } else if (AMAP == 2) {
      int b = m / TC_; int tt = m - b * TC_;
      arow = (size_t)tt * B_ + b;
    } else if (AMAP == 3) {
      int b = m / T_; int tt = m - b * T_;
      arow = (size_t)tt * B_ + b;
    } else {
      arow = (size_t)m;
    }
    short8 v = (short8)0;
    if (8 * c + 8 <= ASRC)
      v = *(const short8*)(A + arow * ASRC + 8 * c);
    *(short8*)(la + row * LDK + 8 * c) = v;
  }
  if (tid < 128) {
    int p = nb * 128 + tid;
    float bv = 0.f;
    if (p < NSRC) {
      int orig = BPERM ? ((p & 3) * 200 + (p >> 2)) : p;
      bv = B1[orig];
      if (BPERM) bv += B2[orig];
    }
    lbias[tid] = bv;
  }
  __syncthreads();

  const int w = tid >> 6, l = tid & 63;
  const int quad = l >> 4, l15 = l & 15;
  const int mq = (w >> 1) * 64, nq = (w & 1) * 64;

  const u16* wrow[4];
#pragma unroll
  for (int nt = 0; nt < 4; ++nt) {
    int p = nb * 128 + nq + nt * 16 + l15;
    wrow[nt] = W + (size_t)((p < NSRC) ? p : 0) * LDK;
  }

  f32x4 acc[4][4];
#pragma unroll
  for (int i = 0; i < 4; ++i)
#pragma unroll
    for (int j = 0; j < 4; ++j) acc[i][j] = (f32x4)0.f;

#pragma unroll
  for (int kt = 0; kt < KT; ++kt) {
    const int k0 = kt * 32 + quad * 8;
    short8 bf[4];
#pragma unroll
    for (int nt = 0; nt < 4; ++nt) bf[nt] = *(const short8*)(wrow[nt] + k0);
    short8 af[4];
#pragma unroll
    for (int mt = 0; mt < 4; ++mt)
      af[mt] = *(const short8*)(la + (mq + mt * 16 + l15) * LDK + k0);
#pragma unroll
    for (int mt = 0; mt < 4; ++mt)
#pragma unroll
      for (int nt = 0; nt < 4; ++nt)
        acc[mt][nt] = __builtin_amdgcn_mfma_f32_16x16x32_bf16(af[mt], bf[nt],
                                                              acc[mt][nt], 0, 0, 0);
  }

#pragma unroll
  for (int mt = 0; mt < 4; ++mt) {
#pragma unroll
    for (int nt = 0; nt < 4; ++nt) {
#pragma unroll
      for (int r = 0; r < 4; ++r) {
        int rowl = mq + mt * 16 + quad * 4 + r;
        int coln = nq + nt * 16 + l15;
        int pg = nb * 128 + coln;
        if (pg < NSTORE) {
          float v = (pg < NSRC) ? (acc[mt][nt][r] + lbias[coln]) : 0.f;
          if (ACT == 1) v = fmaxf(v, 0.f);
          if (ACT == 2) v = sigm(v);
          size_t m = (size_t)mb * 128 + rowl;
          if (OUTM == 0) {
            ((u16*)outv)[m * (size_t)ldout + pg] = f2bf(v);
          } else {
            int b = (int)(m / T_);
            int t = (int)(m - (size_t)b * T_);
            ((float*)outv)[((size_t)b * 129 + pg) * T_ + t] = v;
          }
        }
      }
    }
  }
}

// ---------------------------------------------------------------------------
// Persistent LSTM recurrence, 16 waves (1024 thr). R1-verified structure:
// waves 0,1 own 4 N-tile slots (w, w+16, w+32, w+48), waves 2..15 own 3;
// k-tiles 0..3 register-resident (wreg[4][4]); k-tiles 4,5 in LDS with
// per-lane-contiguous layout (lane*16B, conflict-free); k-tile 6 compact
// quad0 table. Single hbuf, TWO barriers/step (R1-measured-best sync).
// h output in [t][256][200] layout; h(t-1) stored via wide LDS-readback:
// 400 threads x ds_read_b128 + global_store_dwordx4 (contiguous 6.4KB),
// issued at top-of-step so the vmcnt queue drains before the xv wait.
// ---------------------------------------------------------------------------
__device__ __forceinline__ void rec_body(const u16* __restrict__ xg,
                                         const u16* __restrict__ whh,
                                         u16* __restrict__ hout,        // [t][256][200] chunk base
                                         const u16* __restrict__ hprev, // [256][200] row block of h(t0-1)
                                         float* __restrict__ cst, int has_prev,
                                         int blk, char* smem) {
  u16* hb  = (u16*)smem;                    // 16*HSTR u16     =   7,424 B
  u16* w45 = (u16*)(smem + 7424);           // [50][2][512]u16 = 102,400 B
  u16* w6  = (u16*)(smem + 109824);         // [50][128]u16    =  12,800 B

  const int tid = threadIdx.x;
  const int w = tid >> 6, l = tid & 63;
  const int quad = l >> 4, l15 = l & 15;
  const int b0 = blk * 16;
  const bool four = (w < 2);                // waves 0,1 own tiles 48,49 as slot 3

  // ---- prologue: weight caches ----
  short8 wreg[4][4];                        // k-tiles 0..3
#pragma unroll
  for (int s = 0; s < 4; ++s) {
    const bool act = (s < 3) || four;
    int tile = w + 16 * s;
    int p = tile * 16 + l15;
    int orig = (p & 3) * 200 + (p >> 2);
    const u16* wb = whh + (size_t)orig * HID;
#pragma unroll
    for (int kk = 0; kk < 4; ++kk)
      wreg[s][kk] = act ? *(const short8*)(wb + kk * 32 + quad * 8) : (short8)0;
    if (act) {
#pragma unroll
      for (int j = 0; j < 2; ++j)           // kt4,5 -> per-lane-contiguous LDS
        *(short8*)(w45 + (tile * 2 + j) * 512 + l * 8) =
            *(const short8*)(wb + (4 + j) * 32 + quad * 8);
      if (quad == 0)                        // kt6 compact: cols 192..199
        *(short8*)(w6 + tile * 128 + l15 * 8) = *(const short8*)(wb + 192);
    }
  }
  // zero pad cols 200..231 of hbuf (512 entries, one per thread tid<512)
  if (tid < 512) {
    int r = tid >> 5, cc = tid & 31;
    hb[r * HSTR + 200 + cc] = 0;
  }

  // ---- state: slot s -> (batch l15, unit (w+16s)*4+quad) ----
  float c[4]; u16 hreg[4];
#pragma unroll
  for (int s = 0; s < 4; ++s) { c[s] = 0.f; hreg[s] = 0; }
  float* cstp = cst + (size_t)(b0 + l15) * HID;
  if (has_prev) {
#pragma unroll
    for (int s = 0; s < 3; ++s) {
      int unit = (w + 16 * s) * 4 + quad;
      hreg[s] = hprev[(size_t)(b0 + l15) * HID + unit];
      c[s] = cstp[unit];
    }
    if (four) {
      int unit = (w + 48) * 4 + quad;
      hreg[3] = hprev[(size_t)(b0 + l15) * HID + unit];
      c[3] = cstp[unit];
    }
  }

  // xg gather base + first prefetch (slot stride = 16 tiles = 256 u16)
  const u16* xptr = xg + (size_t)(b0 + l15) * TC_ * G4 + w * 16 + quad * 4;
  u16x4 xv[4];
#pragma unroll
  for (int s = 0; s < 3; ++s) xv[s] = *(const u16x4*)(xptr + s * 256);
  xv[3] = four ? *(const u16x4*)(xptr + 768) : (u16x4)0;

  __syncthreads();  // prologue fence (w45/w6 + pad zeros visible)

  for (int t = 0; t < TC_; ++t) {
    // publish h(t-1) to LDS
#pragma unroll
    for (int s = 0; s < 3; ++s)
      hb[l15 * HSTR + (w + 16 * s) * 4 + quad] = hreg[s];
    if (four)
      hb[l15 * HSTR + (w + 48) * 4 + quad] = hreg[3];
    BARRIER_LGKM();  // sync_a

    // wide global store of h(t-1) from LDS: 400 threads x 16B, contiguous
    if (t > 0 && tid < 400) {
      int row = tid / 25, seg = tid - row * 25;
      *(short8*)(hout + (size_t)(t - 1) * HROW + (size_t)(b0 + row) * HID + seg * 8) =
          *(const short8*)(hb + row * HSTR + seg * 8);
    }

    // ---- gates^T = Whh_perm @ h(t-1)^T ----
    f32x4 acc[4];
#pragma unroll
    for (int s = 0; s < 4; ++s) acc[s] = (f32x4)0.f;

#pragma unroll
    for (int kk = 0; kk < 4; ++kk) {        // k-tiles 0..3 from registers
      short8 hf = *(const short8*)(hb + l15 * HSTR + kk * 32 + quad * 8);
      acc[0] = __builtin_amdgcn_mfma_f32_16x16x32_bf16(wreg[0][kk], hf, acc[0], 0, 0, 0);
      acc[1] = __builtin_amdgcn_mfma_f32_16x16x32_bf16(wreg[1][kk], hf, acc[1], 0, 0, 0);
      acc[2] = __builtin_amdgcn_mfma_f32_16x16x32_bf16(wreg[2][kk], hf, acc[2], 0, 0, 0);
      if (four)
        acc[3] = __builtin_amdgcn_mfma_f32_16x16x32_bf16(wreg[3][kk], hf, acc[3], 0, 0, 0);
    }
#pragma unroll
    for (int j = 0; j < 2; ++j) {           // k-tiles 4,5 from LDS (conflict-free)
      short8 hf = *(const short8*)(hb + l15 * HSTR + (4 + j) * 32 + quad * 8);
#pragma unroll
      for (int s = 0; s < 3; ++s) {
        short8 wz = *(const short8*)(w45 + ((w + 16 * s) * 2 + j) * 512 + l * 8);
        acc[s] = __builtin_amdgcn_mfma_f32_16x16x32_bf16(wz, hf, acc[s], 0, 0, 0);
      }
      if (four) {
        short8 wz = *(const short8*)(w45 + ((w + 48) * 2 + j) * 512 + l * 8);
        acc[3] = __builtin_amdgcn_mfma_f32_16x16x32_bf16(wz, hf, acc[3], 0, 0, 0);
      }
    }
    {  // tail k-tile 6: h cols 192..199 real, 200..223 zero-padded
      short8 hf = *(const short8*)(hb + l15 * HSTR + 192 + quad * 8);
#pragma unroll
      for (int s = 0; s < 3; ++s) {
        short8 wz = (short8)0;
        if (quad == 0)
          wz = *(const short8*)(w6 + (w + 16 * s) * 128 + l15 * 8);
        acc[s] = __builtin_amdgcn_mfma_f32_16x16x32_bf16(wz, hf, acc[s], 0, 0, 0);
      }
      if (four) {
        short8 wz = (short8)0;
        if (quad == 0)
          wz = *(const short8*)(w6 + (w + 48) * 128 + l15 * 8);
        acc[3] = __builtin_amdgcn_mfma_f32_16x16x32_bf16(wz, hf, acc[3], 0, 0, 0);
      }
    }

    // ---- lane-local cell update: acc[s][0..3] = i,f,g,o pre-acts ----
#pragma unroll
    for (int s = 0; s < 4; ++s) {
      if (s == 3 && !four) break;
      float vi = acc[s][0] + bf2f(xv[s][0]);
      float vf = acc[s][1] + bf2f(xv[s][1]);
      float vg = acc[s][2] + bf2f(xv[s][2]);
      float vo = acc[s][3] + bf2f(xv[s][3]);
      float iv = sigm(vi);
      float fv = sigm(vf);
      float gv = 2.f * sigm(2.f * vg) - 1.f;  // tanh
      float ov = sigm(vo);
      float cn = fv * c[s] + iv * gv;
      c[s] = cn;
      float th = 2.f * sigm(2.f * cn) - 1.f;
      hreg[s] = f2bf(ov * th);
    }

    // prefetch xg(t+1)
    if (t + 1 < TC_) {
      const u16* xp = xptr + (size_t)(t + 1) * G4;
#pragma unroll
      for (int s = 0; s < 3; ++s) xv[s] = *(const u16x4*)(xp + s * 256);
      if (four) xv[3] = *(const u16x4*)(xp + 768);
    }
    BARRIER_ONLY();  // sync_b: all hbuf reads already register-consumed
  }

  // epilogue: h(TC-1) scatter store + carry state
#pragma unroll
  for (int s = 0; s < 3; ++s) {
    int unit = (w + 16 * s) * 4 + quad;
    hout[(size_t)(TC_ - 1) * HROW + (size_t)(b0 + l15) * HID + unit] = hreg[s];
    cstp[unit] = c[s];
  }
  if (four) {
    int unit = (w + 48) * 4 + quad;
    hout[(size_t)(TC_ - 1) * HROW + (size_t)(b0 + l15) * HID + unit] = hreg[3];
    cstp[unit] = c[3];
  }
}

// Dual-role recurrence: blocks [0,nA) run param set A (layer-1 chunk),
// blocks [nA,grid) run set B (layer-2 chunk), on disjoint CUs.
__global__ __launch_bounds__(1024) void recp_k(
    const u16* __restrict__ xgA, const u16* __restrict__ whhA,
    u16* __restrict__ hA, const u16* __restrict__ hpA, int prevA,
    float* __restrict__ cstA,
    const u16* __restrict__ xgB, const u16* __restrict__ whhB,
    u16* __restrict__ hB, const u16* __restrict__ hpB, int prevB,
    float* __restrict__ cstB, int nA) {
  __shared__ __align__(16) char smem[122624];
  const int bb = blockIdx.x;
  if (bb < nA) rec_body(xgA, whhA, hA, hpA, cstA, prevA, bb, smem);
  else         rec_body(xgB, whhB, hB, hpB, cstB, prevB, bb - nA, smem);
}

// ---------------------------------------------------------------------------
extern "C" void kernel_launch(void* const* d_in, const int* in_sizes, int n_in,
                              void* d_out, int out_size, void* d_ws, size_t ws_size,
                              hipStream_t stream) {
  (void)in_sizes; (void)n_in; (void)out_size; (void)ws_size;
  const float* x     = (const float*)d_in[0];
  const float* w_ih1 = (const float*)d_in[1];
  const float* w_hh1 = (const float*)d_in[2];
  const float* b_ih1 = (const float*)d_in[3];
  const float* b_hh1 = (const float*)d_in[4];
  const float* w_ih2 = (const float*)d_in[5];
  const float* w_hh2 = (const float*)d_in[6];
  const float* b_ih2 = (const float*)d_in[7];
  const float* b_hh2 = (const float*)d_in[8];
  const float* fc1_w = (const float*)d_in[9];
  const float* fc1_b = (const float*)d_in[10];
  const float* fc2_w = (const float*)d_in[11];
  const float* fc2_b = (const float*)d_in[12];
  float* out = (float*)d_out;

  // workspace layout (bytes, 16-aligned); total ~146.1 MB
  char* ws = (char*)d_ws;
  u16*   xgA   = (u16*)(ws);                     //  30,720,000  [256][75][800]
  u16*   xgB   = (u16*)(ws + 30720000LL);        //  30,720,000
  u16*   h2    = (u16*)(ws + 61440000LL);        //  61,440,000  [600][256][200]
  u16*   h1c0  = (u16*)(ws + 122880000LL);       //   7,680,000  [75][256][200]
  u16*   h1c1  = (u16*)(ws + 130560000LL);       //   7,680,000
  u16*   xTq   = (u16*)(ws + 138240000LL);       //   6,144,000  [256][75][160]
  float* cst1  = (float*)(ws + 144384000LL);     //     204,800  [256][200] f32
  float* cst2  = (float*)(ws + 144588800LL);     //     204,800
  u16*   wp1   = (u16*)(ws + 144793600LL);       //     256,000  [800][160]
  u16*   wp2   = (u16*)(ws + 145049600LL);       //     358,400  [800][224]
  u16*   fc1p  = (u16*)(ws + 145408000LL);       //      57,792  [129][224]
  u16*   fc2p  = (u16*)(ws + 145465792LL);       //      41,280  [129][160]
  u16*   whh1c = (u16*)(ws + 145507072LL);       //     320,000  [800][200]
  u16*   whh2c = (u16*)(ws + 145827072LL);       //     320,000  [800][200]
  u16*   y1    = (u16*)(ws);                     // alias xgA/xgB after pipeline

  u16* h1c[2] = {h1c0, h1c1};

  padperm_k<<<(800 * 160 + 255) / 256, 256, 0, stream>>>(w_ih1, wp1, 800, 800, 129, 160, 1);
  padperm_k<<<(800 * 224 + 255) / 256, 256, 0, stream>>>(w_ih2, wp2, 800, 800, 200, 224, 1);
  padperm_k<<<(129 * 224 + 255) / 256, 256, 0, stream>>>(fc1_w, fc1p, 129, 129, 200, 224, 0);
  padperm_k<<<(129 * 160 + 255) / 256, 256, 0, stream>>>(fc2_w, fc2p, 129, 129, 129, 160, 0);
  padperm_k<<<(800 * 200 + 255) / 256, 256, 0, stream>>>(w_hh1, whh1c, 800, 800, 200, 200, 0);
  padperm_k<<<(800 * 200 + 255) / 256, 256, 0, stream>>>(w_hh2, whh2c, 800, 800, 200, 200, 0);

  // ---- software pipeline: rec1(c_{i+1}) runs concurrently with rec2(c_i) ----
  // stage 0: layer-1 chunk 0 alone
  transpose_k<<<dim3(2, 256), 256, 0, stream>>>(x, xTq, 0);
  gemm_k<160, 160, 800, 800, 1, 0, 0, 0>
      <<<dim3(150, 7), 256, 0, stream>>>(xTq, wp1, b_ih1, b_hh1, xgA, 800, 0);
  recp_k<<<dim3(16), 1024, 0, stream>>>(xgA, whh1c, h1c0, h1c0, 0, cst1,
                                        xgA, whh1c, h1c0, h1c0, 0, cst1, 16);

  // stages 1..7: fused (layer-1 chunk i+1 || layer-2 chunk i)
  for (int i = 0; i < 7; ++i) {
    const int tB = i * TC_;
    transpose_k<<<dim3(2, 256), 256, 0, stream>>>(x, xTq, (i + 1) * TC_);
    gemm_k<160, 160, 800, 800, 1, 0, 0, 0>
        <<<dim3(150, 7), 256, 0, stream>>>(xTq, wp1, b_ih1, b_hh1, xgA, 800, 0);
    gemm_k<200, 224, 800, 800, 1, 0, 0, 2>
        <<<dim3(150, 7), 256, 0, stream>>>(h1c[i & 1], wp2, b_ih2, b_hh2, xgB, 800, 0);
    recp_k<<<dim3(32), 1024, 0, stream>>>(
        /*A: layer-1 chunk i+1*/
        xgA, whh1c, h1c[(i + 1) & 1], h1c[i & 1] + (size_t)(TC_ - 1) * HROW, 1, cst1,
        /*B: layer-2 chunk i*/
        xgB, whh2c, h2 + (size_t)tB * HROW,
        (i >= 1) ? (h2 + (size_t)(tB - 1) * HROW) : h2, (i >= 1) ? 1 : 0, cst2, 16);
  }

  // stage 8: layer-2 chunk 7 alone
  gemm_k<200, 224, 800, 800, 1, 0, 0, 2>
      <<<dim3(150, 7), 256, 0, stream>>>(h1c[7 & 1], wp2, b_ih2, b_hh2, xgB, 800, 0);
  recp_k<<<dim3(16), 1024, 0, stream>>>(
      xgA, whh1c, h1c0, h1c0, 0, cst1,
      xgB, whh2c, h2 + (size_t)(7 * TC_) * HROW, h2 + (size_t)(7 * TC_ - 1) * HROW, 1,
      cst2, 0);

  // y1 = relu(h2 @ fc1^T + b); h2 is [600][256][200] -> AMAP=3
  gemm_k<200, 224, 129, 144, 0, 1, 0, 3>
      <<<dim3(1200, 2), 256, 0, stream>>>(h2, fc1p, fc1_b, fc1_b, y1, 144, 0);
  // out = sigmoid(y1 @ fc2^T + b), f32 scatter to [B][129][T]
  gemm_k<144, 160, 129, 129, 0, 2, 1, 0>
      <<<dim3(1200, 2), 256, 0, stream>>>(y1, fc2p, fc2_b, fc2_b, out, 0, 0);
}

// Round 9
// 2291.837 us; speedup vs baseline: 1.4060x; 1.1126x over previous
//
#include <hip/hip_runtime.h>

typedef unsigned short u16;
typedef short short8 __attribute__((ext_vector_type(8)));
typedef float f32x4 __attribute__((ext_vector_type(4)));
typedef unsigned short u16x4 __attribute__((ext_vector_type(4)));

#define B_  256
#define T_  600
#define TC_ 75    // time chunk (8 chunks)
#define HID 200
#define G4  800
#define HSTR 232  // hbuf row stride (u16): 464B -> 2-way bank aliasing only (free)
#define HROW (B_ * HID)  // 51200 u16 per time-row in [t][b][200] layout

__device__ __forceinline__ float bf2f(u16 u) {
  union { unsigned int i; float f; } v; v.i = ((unsigned int)u) << 16; return v.f;
}
__device__ __forceinline__ u16 f2bf(float f) {
  union { float f; unsigned int i; } v; v.f = f;
  unsigned int r = v.i + 0x7FFFu + ((v.i >> 16) & 1u);
  return (u16)(r >> 16);
}
__device__ __forceinline__ float sigm(float x) {
  float e = __expf(-x);
  return __builtin_amdgcn_rcpf(1.f + e);
}

// sync_a: LDS writes must be visible; global ops may remain in flight.
#define BARRIER_LGKM() asm volatile("s_waitcnt lgkmcnt(0)\n\ts_barrier" ::: "memory")
// sync_b: all LDS reads already register-consumed; just rendezvous.
#define BARRIER_ONLY() asm volatile("s_barrier" ::: "memory")

// ---------------------------------------------------------------------------
// Pad / permute / downcast f32 weights into aligned bf16 scratch.
// ---------------------------------------------------------------------------
__global__ __launch_bounds__(256) void padperm_k(const float* __restrict__ src,
                                                 u16* __restrict__ dst,
                                                 int rows, int srows, int scols,
                                                 int dcols, int perm) {
  int idx = blockIdx.x * 256 + threadIdx.x;
  if (idx >= rows * dcols) return;
  int r = idx / dcols, c = idx - r * dcols;
  int sr = perm ? ((r & 3) * 200 + (r >> 2)) : r;
  dst[idx] = (r < srows && c < scols) ? f2bf(src[(size_t)sr * scols + c]) : (u16)0;
}

// ---------------------------------------------------------------------------
// Transpose chunk (standalone, prologue): x [B][129][600] f32 -> xTq bf16.
// ---------------------------------------------------------------------------
__global__ __launch_bounds__(256) void transpose_k(const float* __restrict__ x,
                                                   u16* __restrict__ xTq, int t0) {
  __shared__ u16 tile[129 * 65];
  const int b = blockIdx.y;
  const int tt0 = blockIdx.x * 64;
  const int tid = threadIdx.x;
  for (int idx = tid; idx < 129 * 64; idx += 256) {
    int i = idx >> 6, tt = idx & 63;
    int t = t0 + tt0 + tt;
    tile[i * 65 + tt] = (tt0 + tt < TC_ && t < T_)
        ? f2bf(x[((size_t)b * 129 + i) * T_ + t]) : (u16)0;
  }
  __syncthreads();
  for (int idx = tid; idx < 64 * 160; idx += 256) {
    int tt = idx / 160, i = idx - tt * 160;
    if (tt0 + tt < TC_)
      xTq[((size_t)b * TC_ + tt0 + tt) * 160 + i] = (i < 129) ? tile[i * 65 + tt] : (u16)0;
  }
}

// ---------------------------------------------------------------------------
// GEMM: out = ACT(A @ W^T + bias). AMAP selects the A-row mapping:
//   0: arow = m
//   2: m=(b,tt) in chunk -> arow = tt*B_ + b           (A = chunk [tt][256][*])
//   3: m=(b,t)  full     -> arow = t*B_ + b            (A = [600][256][*])
// ---------------------------------------------------------------------------
template<int ASRC, int LDK, int NSRC, int NSTORE, int BPERM, int ACT, int OUTM, int AMAP>
__global__ __launch_bounds__(256, 2) void gemm_k(
    const u16* __restrict__ A, const u16* __restrict__ W,
    const float* __restrict__ B1, const float* __restrict__ B2,
    void* __restrict__ outv, int ldout, int t0) {
  constexpr int NCH = LDK / 8;
  constexpr int KT = LDK / 32;
  __shared__ u16 la[128 * LDK];
  __shared__ float lbias[128];
  const int tid = threadIdx.x;
  const int mb = blockIdx.x, nb = blockIdx.y;

  for (int idx = tid; idx < 128 * NCH; idx += 256) {
    int row = idx / NCH, c = idx - row * NCH;
    int m = mb * 128 + row;
    size_t arow;
    if (AMAP == 2) {
      int b = m / TC_; int tt = m - b * TC_;
      arow = (size_t)tt * B_ + b;
    } else if (AMAP == 3) {
      int b = m / T_; int tt = m - b * T_;
      arow = (size_t)tt * B_ + b;
    } else {
      arow = (size_t)m;
    }
    short8 v = (short8)0;
    if (8 * c + 8 <= ASRC)
      v = *(const short8*)(A + arow * ASRC + 8 * c);
    *(short8*)(la + row * LDK + 8 * c) = v;
  }
  if (tid < 128) {
    int p = nb * 128 + tid;
    float bv = 0.f;
    if (p < NSRC) {
      int orig = BPERM ? ((p & 3) * 200 + (p >> 2)) : p;
      bv = B1[orig];
      if (BPERM) bv += B2[orig];
    }
    lbias[tid] = bv;
  }
  __syncthreads();

  const int w = tid >> 6, l = tid & 63;
  const int quad = l >> 4, l15 = l & 15;
  const int mq = (w >> 1) * 64, nq = (w & 1) * 64;

  const u16* wrow[4];
#pragma unroll
  for (int nt = 0; nt < 4; ++nt) {
    int p = nb * 128 + nq + nt * 16 + l15;
    wrow[nt] = W + (size_t)((p < NSRC) ? p : 0) * LDK;
  }

  f32x4 acc[4][4];
#pragma unroll
  for (int i = 0; i < 4; ++i)
#pragma unroll
    for (int j = 0; j < 4; ++j) acc[i][j] = (f32x4)0.f;

#pragma unroll
  for (int kt = 0; kt < KT; ++kt) {
    const int k0 = kt * 32 + quad * 8;
    short8 bf[4];
#pragma unroll
    for (int nt = 0; nt < 4; ++nt) bf[nt] = *(const short8*)(wrow[nt] + k0);
    short8 af[4];
#pragma unroll
    for (int mt = 0; mt < 4; ++mt)
      af[mt] = *(const short8*)(la + (mq + mt * 16 + l15) * LDK + k0);
#pragma unroll
    for (int mt = 0; mt < 4; ++mt)
#pragma unroll
      for (int nt = 0; nt < 4; ++nt)
        acc[mt][nt] = __builtin_amdgcn_mfma_f32_16x16x32_bf16(af[mt], bf[nt],
                                                              acc[mt][nt], 0, 0, 0);
  }

#pragma unroll
  for (int mt = 0; mt < 4; ++mt) {
#pragma unroll
    for (int nt = 0; nt < 4; ++nt) {
#pragma unroll
      for (int r = 0; r < 4; ++r) {
        int rowl = mq + mt * 16 + quad * 4 + r;
        int coln = nq + nt * 16 + l15;
        int pg = nb * 128 + coln;
        if (pg < NSTORE) {
          float v = (pg < NSRC) ? (acc[mt][nt][r] + lbias[coln]) : 0.f;
          if (ACT == 1) v = fmaxf(v, 0.f);
          if (ACT == 2) v = sigm(v);
          size_t m = (size_t)mb * 128 + rowl;
          if (OUTM == 0) {
            ((u16*)outv)[m * (size_t)ldout + pg] = f2bf(v);
          } else {
            int b = (int)(m / T_);
            int t = (int)(m - (size_t)b * T_);
            ((float*)outv)[((size_t)b * 129 + pg) * T_ + t] = v;
          }
        }
      }
    }
  }
}

// ---------------------------------------------------------------------------
// Persistent LSTM recurrence body — byte-identical to the R8-verified version
// (188 us/dispatch). 16 waves; waves 0,1 own 4 N-tile slots, waves 2..15 own
// 3; kt0..3 register-resident, kt4,5 per-lane-contiguous LDS (conflict-free),
// kt6 compact quad0 table. Single hbuf, two barriers/step, wide LDS-readback
// h-store at top-of-step.
// ---------------------------------------------------------------------------
__device__ __forceinline__ void rec_body(const u16* __restrict__ xg,
                                         const u16* __restrict__ whh,
                                         u16* __restrict__ hout,        // [t][256][200] chunk base
                                         const u16* __restrict__ hprev, // [256][200] row of h(t0-1)
                                         float* __restrict__ cst, int has_prev,
                                         int blk, char* smem) {
  u16* hb  = (u16*)smem;                    // 16*HSTR u16     =   7,424 B
  u16* w45 = (u16*)(smem + 7424);           // [50][2][512]u16 = 102,400 B
  u16* w6  = (u16*)(smem + 109824);         // [50][128]u16    =  12,800 B

  const int tid = threadIdx.x;
  const int w = tid >> 6, l = tid & 63;
  const int quad = l >> 4, l15 = l & 15;
  const int b0 = blk * 16;
  const bool four = (w < 2);                // waves 0,1 own tiles 48,49 as slot 3

  // ---- prologue: weight caches ----
  short8 wreg[4][4];                        // k-tiles 0..3
#pragma unroll
  for (int s = 0; s < 4; ++s) {
    const bool act = (s < 3) || four;
    int tile = w + 16 * s;
    int p = tile * 16 + l15;
    int orig = (p & 3) * 200 + (p >> 2);
    const u16* wb = whh + (size_t)orig * HID;
#pragma unroll
    for (int kk = 0; kk < 4; ++kk)
      wreg[s][kk] = act ? *(const short8*)(wb + kk * 32 + quad * 8) : (short8)0;
    if (act) {
#pragma unroll
      for (int j = 0; j < 2; ++j)           // kt4,5 -> per-lane-contiguous LDS
        *(short8*)(w45 + (tile * 2 + j) * 512 + l * 8) =
            *(const short8*)(wb + (4 + j) * 32 + quad * 8);
      if (quad == 0)                        // kt6 compact: cols 192..199
        *(short8*)(w6 + tile * 128 + l15 * 8) = *(const short8*)(wb + 192);
    }
  }
  // zero pad cols 200..231 of hbuf
  if (tid < 512) {
    int r = tid >> 5, cc = tid & 31;
    hb[r * HSTR + 200 + cc] = 0;
  }

  // ---- state: slot s -> (batch l15, unit (w+16s)*4+quad) ----
  float c[4]; u16 hreg[4];
#pragma unroll
  for (int s = 0; s < 4; ++s) { c[s] = 0.f; hreg[s] = 0; }
  float* cstp = cst + (size_t)(b0 + l15) * HID;
  if (has_prev) {
#pragma unroll
    for (int s = 0; s < 3; ++s) {
      int unit = (w + 16 * s) * 4 + quad;
      hreg[s] = hprev[(size_t)(b0 + l15) * HID + unit];
      c[s] = cstp[unit];
    }
    if (four) {
      int unit = (w + 48) * 4 + quad;
      hreg[3] = hprev[(size_t)(b0 + l15) * HID + unit];
      c[3] = cstp[unit];
    }
  }

  // xg gather base + first prefetch (slot stride = 16 tiles = 256 u16)
  const u16* xptr = xg + (size_t)(b0 + l15) * TC_ * G4 + w * 16 + quad * 4;
  u16x4 xv[4];
#pragma unroll
  for (int s = 0; s < 3; ++s) xv[s] = *(const u16x4*)(xptr + s * 256);
  xv[3] = four ? *(const u16x4*)(xptr + 768) : (u16x4)0;

  __syncthreads();  // prologue fence (w45/w6 + pad zeros visible)

  for (int t = 0; t < TC_; ++t) {
    // publish h(t-1) to LDS
#pragma unroll
    for (int s = 0; s < 3; ++s)
      hb[l15 * HSTR + (w + 16 * s) * 4 + quad] = hreg[s];
    if (four)
      hb[l15 * HSTR + (w + 48) * 4 + quad] = hreg[3];
    BARRIER_LGKM();  // sync_a

    // wide global store of h(t-1) from LDS: 400 threads x 16B, contiguous
    if (t > 0 && tid < 400) {
      int row = tid / 25, seg = tid - row * 25;
      *(short8*)(hout + (size_t)(t - 1) * HROW + (size_t)(b0 + row) * HID + seg * 8) =
          *(const short8*)(hb + row * HSTR + seg * 8);
    }

    // ---- gates^T = Whh_perm @ h(t-1)^T ----
    f32x4 acc[4];
#pragma unroll
    for (int s = 0; s < 4; ++s) acc[s] = (f32x4)0.f;

#pragma unroll
    for (int kk = 0; kk < 4; ++kk) {        // k-tiles 0..3 from registers
      short8 hf = *(const short8*)(hb + l15 * HSTR + kk * 32 + quad * 8);
      acc[0] = __builtin_amdgcn_mfma_f32_16x16x32_bf16(wreg[0][kk], hf, acc[0], 0, 0, 0);
      acc[1] = __builtin_amdgcn_mfma_f32_16x16x32_bf16(wreg[1][kk], hf, acc[1], 0, 0, 0);
      acc[2] = __builtin_amdgcn_mfma_f32_16x16x32_bf16(wreg[2][kk], hf, acc[2], 0, 0, 0);
      if (four)
        acc[3] = __builtin_amdgcn_mfma_f32_16x16x32_bf16(wreg[3][kk], hf, acc[3], 0, 0, 0);
    }
#pragma unroll
    for (int j = 0; j < 2; ++j) {           // k-tiles 4,5 from LDS (conflict-free)
      short8 hf = *(const short8*)(hb + l15 * HSTR + (4 + j) * 32 + quad * 8);
#pragma unroll
      for (int s = 0; s < 3; ++s) {
        short8 wz = *(const short8*)(w45 + ((w + 16 * s) * 2 + j) * 512 + l * 8);
        acc[s] = __builtin_amdgcn_mfma_f32_16x16x32_bf16(wz, hf, acc[s], 0, 0, 0);
      }
      if (four) {
        short8 wz = *(const short8*)(w45 + ((w + 48) * 2 + j) * 512 + l * 8);
        acc[3] = __builtin_amdgcn_mfma_f32_16x16x32_bf16(wz, hf, acc[3], 0, 0, 0);
      }
    }
    {  // tail k-tile 6: h cols 192..199 real, 200..223 zero-padded
      short8 hf = *(const short8*)(hb + l15 * HSTR + 192 + quad * 8);
#pragma unroll
      for (int s = 0; s < 3; ++s) {
        short8 wz = (short8)0;
        if (quad == 0)
          wz = *(const short8*)(w6 + (w + 16 * s) * 128 + l15 * 8);
        acc[s] = __builtin_amdgcn_mfma_f32_16x16x32_bf16(wz, hf, acc[s], 0, 0, 0);
      }
      if (four) {
        short8 wz = (short8)0;
        if (quad == 0)
          wz = *(const short8*)(w6 + (w + 48) * 128 + l15 * 8);
        acc[3] = __builtin_amdgcn_mfma_f32_16x16x32_bf16(wz, hf, acc[3], 0, 0, 0);
      }
    }

    // ---- lane-local cell update: acc[s][0..3] = i,f,g,o pre-acts ----
#pragma unroll
    for (int s = 0; s < 4; ++s) {
      if (s == 3 && !four) break;
      float vi = acc[s][0] + bf2f(xv[s][0]);
      float vf = acc[s][1] + bf2f(xv[s][1]);
      float vg = acc[s][2] + bf2f(xv[s][2]);
      float vo = acc[s][3] + bf2f(xv[s][3]);
      float iv = sigm(vi);
      float fv = sigm(vf);
      float gv = 2.f * sigm(2.f * vg) - 1.f;  // tanh
      float ov = sigm(vo);
      float cn = fv * c[s] + iv * gv;
      c[s] = cn;
      float th = 2.f * sigm(2.f * cn) - 1.f;
      hreg[s] = f2bf(ov * th);
    }

    // prefetch xg(t+1)
    if (t + 1 < TC_) {
      const u16* xp = xptr + (size_t)(t + 1) * G4;
#pragma unroll
      for (int s = 0; s < 3; ++s) xv[s] = *(const u16x4*)(xp + s * 256);
      if (four) xv[3] = *(const u16x4*)(xp + 768);
    }
    BARRIER_ONLY();  // sync_b: all hbuf reads already register-consumed
  }

  // epilogue: h(TC-1) scatter store + carry state
#pragma unroll
  for (int s = 0; s < 3; ++s) {
    int unit = (w + 16 * s) * 4 + quad;
    hout[(size_t)(TC_ - 1) * HROW + (size_t)(b0 + l15) * HID + unit] = hreg[s];
    cstp[unit] = c[s];
  }
  if (four) {
    int unit = (w + 48) * 4 + quad;
    hout[(size_t)(TC_ - 1) * HROW + (size_t)(b0 + l15) * HID + unit] = hreg[3];
    cstp[unit] = c[3];
  }
}

// ---------------------------------------------------------------------------
// 1024-thread gemm1 role: xg1 chunk = xTq @ wp1^T + (b_ih1+b_hh1) (permuted).
// Block = 2 M-passes of 128 rows x 512 cols; grid 150 (75 m-pairs x 2 nb).
// ---------------------------------------------------------------------------
__device__ __forceinline__ void gemm1_body(const u16* __restrict__ A,
                                           const u16* __restrict__ W,
                                           const float* __restrict__ B1,
                                           const float* __restrict__ B2,
                                           u16* __restrict__ out, int bb,
                                           char* smem) {
  u16* la = (u16*)smem;                    // [128][160] = 40960 B
  float* lbias = (float*)(smem + 40960);   // [512]      =  2048 B
  const int tid = threadIdx.x;
  const int mpair = bb >> 1, nb = bb & 1;

  if (tid < 512) {
    int p = nb * 512 + tid;
    float bv = 0.f;
    if (p < 800) { int orig = (p & 3) * 200 + (p >> 2); bv = B1[orig] + B2[orig]; }
    lbias[tid] = bv;
  }

  const int w = tid >> 6, l = tid & 63;
  const int quad = l >> 4, l15 = l & 15;
  const int mq = (w >> 3) * 64, nq = (w & 7) * 64;

  const u16* wrow[4];
#pragma unroll
  for (int nt = 0; nt < 4; ++nt) {
    int p = nb * 512 + nq + nt * 16 + l15;
    wrow[nt] = W + (size_t)((p < 800) ? p : 0) * 160;
  }

  for (int mi = 0; mi < 2; ++mi) {
    const int mb = mpair * 2 + mi;
    if (mi) __syncthreads();  // drain previous pass's la reads
    for (int idx = tid; idx < 128 * 20; idx += 1024) {
      int row = idx / 20, cc = idx - row * 20;
      *(short8*)(la + row * 160 + 8 * cc) =
          *(const short8*)(A + (size_t)(mb * 128 + row) * 160 + 8 * cc);
    }
    __syncthreads();

    f32x4 acc[4][4];
#pragma unroll
    for (int i = 0; i < 4; ++i)
#pragma unroll
      for (int j = 0; j < 4; ++j) acc[i][j] = (f32x4)0.f;

#pragma unroll
    for (int kt = 0; kt < 5; ++kt) {
      const int k0 = kt * 32 + quad * 8;
      short8 bf[4];
#pragma unroll
      for (int nt = 0; nt < 4; ++nt) bf[nt] = *(const short8*)(wrow[nt] + k0);
      short8 af[4];
#pragma unroll
      for (int mt = 0; mt < 4; ++mt)
        af[mt] = *(const short8*)(la + (mq + mt * 16 + l15) * 160 + k0);
#pragma unroll
      for (int mt = 0; mt < 4; ++mt)
#pragma unroll
        for (int nt = 0; nt < 4; ++nt)
          acc[mt][nt] = __builtin_amdgcn_mfma_f32_16x16x32_bf16(af[mt], bf[nt],
                                                                acc[mt][nt], 0, 0, 0);
    }

#pragma unroll
    for (int mt = 0; mt < 4; ++mt) {
#pragma unroll
      for (int nt = 0; nt < 4; ++nt) {
#pragma unroll
        for (int r = 0; r < 4; ++r) {
          int rowl = mq + mt * 16 + quad * 4 + r;
          int coln = nq + nt * 16 + l15;
          int pg = nb * 512 + coln;
          if (pg < 800) {
            float v = acc[mt][nt][r] + lbias[coln];
            out[(size_t)(mb * 128 + rowl) * 800 + pg] = f2bf(v);
          }
        }
      }
    }
  }
}

// ---------------------------------------------------------------------------
// 1024-thread transpose role: 4 slices of 256 threads, each one batch.
// Writes xTq chunk [b][75][160] for window t0.
// ---------------------------------------------------------------------------
__device__ __forceinline__ void transpose_body(const float* __restrict__ x,
                                               u16* __restrict__ xTq, int t0,
                                               int bb, char* smem) {
  const int tid = threadIdx.x;
  const int sl = tid >> 8, stid = tid & 255;
  u16* tile = (u16*)(smem + sl * 16800);    // 129*65 u16 = 16770 B per slice
  const int b = bb * 4 + sl;
  for (int half = 0; half < 2; ++half) {
    const int tt0 = half * 64;
    __syncthreads();  // protect tile reuse across halves (uniform)
    for (int idx = stid; idx < 129 * 64; idx += 256) {
      int i = idx >> 6, tt = idx & 63;
      int t = t0 + tt0 + tt;
      tile[i * 65 + tt] = (tt0 + tt < TC_ && t < T_)
          ? f2bf(x[((size_t)b * 129 + i) * T_ + t]) : (u16)0;
    }
    __syncthreads();
    for (int idx = stid; idx < 64 * 160; idx += 256) {
      int tt = idx / 160, i = idx - tt * 160;
      if (tt0 + tt < TC_)
        xTq[((size_t)b * TC_ + tt0 + tt) * 160 + i] = (i < 129) ? tile[i * 65 + tt] : (u16)0;
    }
  }
}

// ---------------------------------------------------------------------------
// Fused launch, 4 roles on disjoint CUs (each block needs 122KB LDS -> 1/CU;
// grid <= 246 <= 256 CUs):
//   [0,nA)            recA  layer-1 chunk i
//   [nA,nA+nB)        recB  layer-2 chunk i-1
//   [.., +nG)         gemm1 xg1 for chunk i+1 (depends only on xTq)
//   [.., +nT)         transpose xTq for chunk i+2 (depends only on x)
// ---------------------------------------------------------------------------
__global__ __launch_bounds__(1024) void fused_k(
    const u16* __restrict__ xgA, const u16* __restrict__ whhA,
    u16* __restrict__ hA, const u16* __restrict__ hpA, int prevA,
    float* __restrict__ cstA,
    const u16* __restrict__ xgB, const u16* __restrict__ whhB,
    u16* __restrict__ hB, const u16* __restrict__ hpB, int prevB,
    float* __restrict__ cstB,
    const u16* __restrict__ gA, const u16* __restrict__ gW,
    const float* __restrict__ gB1, const float* __restrict__ gB2,
    u16* __restrict__ gOut,
    const float* __restrict__ tX, u16* __restrict__ tOut, int tT0,
    int nA, int nB, int nG, int nT) {
  __shared__ __align__(16) char smem[122624];
  int bb = blockIdx.x;
  if (bb < nA) { rec_body(xgA, whhA, hA, hpA, cstA, prevA, bb, smem); return; }
  bb -= nA;
  if (bb < nB) { rec_body(xgB, whhB, hB, hpB, cstB, prevB, bb, smem); return; }
  bb -= nB;
  if (bb < nG) { gemm1_body(gA, gW, gB1, gB2, gOut, bb, smem); return; }
  bb -= nG;
  if (bb < nT) transpose_body(tX, tOut, tT0, bb, smem);
}

// ---------------------------------------------------------------------------
extern "C" void kernel_launch(void* const* d_in, const int* in_sizes, int n_in,
                              void* d_out, int out_size, void* d_ws, size_t ws_size,
                              hipStream_t stream) {
  (void)in_sizes; (void)n_in; (void)out_size; (void)ws_size;
  const float* x     = (const float*)d_in[0];
  const float* w_ih1 = (const float*)d_in[1];
  const float* w_hh1 = (const float*)d_in[2];
  const float* b_ih1 = (const float*)d_in[3];
  const float* b_hh1 = (const float*)d_in[4];
  const float* w_ih2 = (const float*)d_in[5];
  const float* w_hh2 = (const float*)d_in[6];
  const float* b_ih2 = (const float*)d_in[7];
  const float* b_hh2 = (const float*)d_in[8];
  const float* fc1_w = (const float*)d_in[9];
  const float* fc1_b = (const float*)d_in[10];
  const float* fc2_w = (const float*)d_in[11];
  const float* fc2_b = (const float*)d_in[12];
  float* out = (float*)d_out;

  // workspace layout (bytes, 16-aligned); total ~183.0 MB
  char* ws = (char*)d_ws;
  u16*   xg1a  = (u16*)(ws);                     //  30,720,000  [256][75][800]
  u16*   xg1b  = (u16*)(ws + 30720000LL);        //  30,720,000
  u16*   xg2   = (u16*)(ws + 61440000LL);        //  30,720,000
  u16*   h2    = (u16*)(ws + 92160000LL);        //  61,440,000  [600][256][200]
  u16*   h1c0  = (u16*)(ws + 153600000LL);       //   7,680,000  [75][256][200]
  u16*   h1c1  = (u16*)(ws + 161280000LL);       //   7,680,000
  u16*   xTq0  = (u16*)(ws + 168960000LL);       //   6,144,000  [256][75][160]
  u16*   xTq1  = (u16*)(ws + 175104000LL);       //   6,144,000
  float* cst1  = (float*)(ws + 181248000LL);     //     204,800  [256][200] f32
  float* cst2  = (float*)(ws + 181452800LL);     //     204,800
  u16*   wp1   = (u16*)(ws + 181657600LL);       //     256,000  [800][160]
  u16*   wp2   = (u16*)(ws + 181913600LL);       //     358,400  [800][224]
  u16*   fc1p  = (u16*)(ws + 182272000LL);       //      57,792  [129][224]
  u16*   fc2p  = (u16*)(ws + 182329792LL);       //      41,280  [129][160]
  u16*   whh1c = (u16*)(ws + 182371072LL);       //     320,000  [800][200]
  u16*   whh2c = (u16*)(ws + 182691072LL);       //     320,000  [800][200]
  u16*   y1    = (u16*)(ws);                     // alias xg1a/xg1b after pipeline

  u16* xg1[2] = {xg1a, xg1b};
  u16* xTq[2] = {xTq0, xTq1};
  u16* h1c[2] = {h1c0, h1c1};

  padperm_k<<<(800 * 160 + 255) / 256, 256, 0, stream>>>(w_ih1, wp1, 800, 800, 129, 160, 1);
  padperm_k<<<(800 * 224 + 255) / 256, 256, 0, stream>>>(w_ih2, wp2, 800, 800, 200, 224, 1);
  padperm_k<<<(129 * 224 + 255) / 256, 256, 0, stream>>>(fc1_w, fc1p, 129, 129, 200, 224, 0);
  padperm_k<<<(129 * 160 + 255) / 256, 256, 0, stream>>>(fc2_w, fc2p, 129, 129, 129, 160, 0);
  padperm_k<<<(800 * 200 + 255) / 256, 256, 0, stream>>>(w_hh1, whh1c, 800, 800, 200, 200, 0);
  padperm_k<<<(800 * 200 + 255) / 256, 256, 0, stream>>>(w_hh2, whh2c, 800, 800, 200, 200, 0);

  // prologue: transpose chunks 0,1 and gemm1 chunk 0 (serial)
  transpose_k<<<dim3(2, 256), 256, 0, stream>>>(x, xTq0, 0);
  transpose_k<<<dim3(2, 256), 256, 0, stream>>>(x, xTq1, TC_);
  gemm_k<160, 160, 800, 800, 1, 0, 0, 0>
      <<<dim3(150, 7), 256, 0, stream>>>(xTq0, wp1, b_ih1, b_hh1, xg1a, 800, 0);

  // pipeline: stage i = recA(chunk i) || recB(chunk i-1) || gemm1(i+1) || transpose(i+2)
  // between stages: gemm2(chunk i) serial (critical path: h1c(i) -> xg2 -> recB(i))
  for (int i = 0; i <= 8; ++i) {
    const int nA = (i <= 7) ? 16 : 0;
    const int nB = (i >= 1) ? 16 : 0;
    const int nG = (i <= 6) ? 150 : 0;
    const int nT = (i <= 5) ? 64 : 0;
    const int j = (i >= 1) ? (i - 1) : 0;   // recB chunk index (clamped)
    fused_k<<<dim3(nA + nB + nG + nT), 1024, 0, stream>>>(
        /*A: layer-1 chunk i*/
        xg1[i & 1], whh1c, h1c[i & 1],
        (i >= 1) ? (h1c[(i - 1) & 1] + (size_t)(TC_ - 1) * HROW) : h1c[0], (i >= 1) ? 1 : 0,
        cst1,
        /*B: layer-2 chunk j*/
        xg2, whh2c, h2 + (size_t)j * TC_ * HROW,
        (j >= 1) ? (h2 + ((size_t)j * TC_ - 1) * HROW) : h2, (j >= 1) ? 1 : 0, cst2,
        /*G: gemm1 chunk i+1*/
        xTq[(i + 1) & 1], wp1, b_ih1, b_hh1, xg1[(i + 1) & 1],
        /*T: transpose chunk i+2 -> xTq[i&1]*/
        x, xTq[i & 1], (i + 2) * TC_,
        nA, nB, nG, nT);
    if (i <= 7)  // gemm2 chunk i (consumed by recB in stage i+1)
      gemm_k<200, 224, 800, 800, 1, 0, 0, 2>
          <<<dim3(150, 7), 256, 0, stream>>>(h1c[i & 1], wp2, b_ih2, b_hh2, xg2, 800, 0);
  }

  // y1 = relu(h2 @ fc1^T + b); h2 is [600][256][200] -> AMAP=3
  gemm_k<200, 224, 129, 144, 0, 1, 0, 3>
      <<<dim3(1200, 2), 256, 0, stream>>>(h2, fc1p, fc1_b, fc1_b, y1, 144, 0);
  // out = sigmoid(y1 @ fc2^T + b), f32 scatter to [B][129][T]
  gemm_k<144, 160, 129, 129, 0, 2, 1, 0>
      <<<dim3(1200, 2), 256, 0, stream>>>(y1, fc2p, fc2_b, fc2_b, out, 0, 0);
}